// Round 2
// baseline (974.023 us; speedup 1.0000x reference)
//
#include <hip/hip_runtime.h>
#include <cstdint>
#include <cstddef>

#define NB   4096
#define OBS  512
#define NACT 64
#define NT   10
#define NE   16
#define DREP 1024
#define DH   1024
#define DK   512
#define SLD  (OBS + NT)    // 522, state row length
#define XK   (OBS + NACT)  // 576

typedef short s8v __attribute__((ext_vector_type(8)));  // 8 bf16 in 4 VGPRs
typedef float f4v __attribute__((ext_vector_type(4)));

__device__ __forceinline__ unsigned short f2bf(float f) {
  union { float f; unsigned int u; } v; v.f = f;
  unsigned int u = v.u;
  unsigned int r = (u + 0x7FFFu + ((u >> 16) & 1u)) >> 16;  // RNE
  return (unsigned short)r;
}
__device__ __forceinline__ float bf2f(unsigned short h) {
  union { unsigned int u; float f; } v; v.u = ((unsigned int)h) << 16;
  return v.f;
}

__device__ __forceinline__ void gload_lds16(const unsigned short* gp, const unsigned short* lp) {
  __builtin_amdgcn_global_load_lds(
      (const __attribute__((address_space(1))) void*)(uintptr_t)gp,
      (__attribute__((address_space(3))) void*)(unsigned int)(uintptr_t)lp,
      16, 0, 0);
}

// ---------------------------------------------------------------------------
// Generic bf16 GEMM: C[M,N] = A[M,K] @ Bt[N,K]^T  (Bt is N-major, K contiguous)
// LDS layout: 16B chunks XOR-swizzled: slot s of row r holds logical k-chunk
// s ^ ((r>>1)&3).  Staging swizzles the per-lane GLOBAL k-offset (LDS dest is
// pinned to base+lane*16 by global_load_lds); readers apply the same XOR.
// This spreads frag reads uniformly over the 8 16B-positions per 128B bank
// line -> 2-way aliasing only (free, m136), vs 8-way in the naive layout.
// MODE 0: out = bf16(maybe_relu(C + bias[col]))
// MODE 1 (K-pass): v=relu(C+bk0[e,col]); atomicAdd logits[row,e] += v*qk1[e,task[row],col]
// MODE 2 (V-pass): out = bf16(attn[row,e] * relu(C + bv0[e,col])), e = eBase+blockIdx.z
// MODE 3 (accum):  v = C + cio[row,col]; write fp32 back (outBf=0) or bf16 to outB (outBf=1)
// ---------------------------------------------------------------------------
template <int BM, int BN, int MODE>
__global__ void __launch_bounds__(256)
gemm_k(const unsigned short* __restrict__ A, int lda,
       const unsigned short* __restrict__ Bt, int ldb,
       int K, const float* __restrict__ bias, int relu,
       unsigned short* __restrict__ outB, int ldo,
       const float* __restrict__ qk1, const int* __restrict__ task,
       float* __restrict__ logits, int eBase,
       const float* __restrict__ attn, float* __restrict__ cio, int outBf)
{
  constexpr int FM = BM / 32;   // 16x16 frags per wave (M)
  constexpr int FN = BN / 32;
  constexpr int CA = BM / 64;   // 1KB staging chunks per wave (A)
  constexpr int CB = BN / 64;

  __shared__ __align__(16) unsigned short As[BM * 32];
  __shared__ __align__(16) unsigned short Bs[BN * 32];

  const int tid  = threadIdx.x;
  const int wave = tid >> 6;
  const int lane = tid & 63;
  const int wm = wave >> 1, wn = wave & 1;

  const int rowBase = blockIdx.x * BM;
  const int colBase = blockIdx.y * BN;

  int eg = 0;
  if (MODE == 1) {
    eg = blockIdx.z;
    Bt  += (size_t)eg * (DREP * DH);
    bias += eg * DH;
    qk1 += (size_t)eg * (NT * DH);
  }
  if (MODE == 2) {
    eg = eBase + blockIdx.z;
    Bt  += (size_t)eg * (DREP * DH);
    bias += eg * DH;
    outB += (size_t)blockIdx.z * DH;   // local slab in A'
  }

  f4v acc[FM][FN];
#pragma unroll
  for (int m = 0; m < FM; ++m)
#pragma unroll
    for (int n = 0; n < FN; ++n) acc[m][n] = f4v{0.f, 0.f, 0.f, 0.f};

  const int sRow = lane >> 2;                                 // row within 16-row chunk
  const int sSw  = ((lane & 3) ^ ((sRow >> 1) & 3)) * 8;      // swizzled global k-offset
  const unsigned short* Ag = A  + (size_t)rowBase * lda + sSw;
  const unsigned short* Bg = Bt + (size_t)colBase * ldb + sSw;

  const int fr   = lane & 15;
  const int koSw = (((lane >> 4) ^ ((fr >> 1) & 3)) * 8);     // swizzled read slot

  for (int kt = 0; kt < K; kt += 32) {
    __syncthreads();
#pragma unroll
    for (int j = 0; j < CA; ++j) {
      int chunk = wave * CA + j;
      gload_lds16(Ag + (size_t)(chunk * 16 + sRow) * lda + kt, As + chunk * 512);
    }
#pragma unroll
    for (int j = 0; j < CB; ++j) {
      int chunk = wave * CB + j;
      gload_lds16(Bg + (size_t)(chunk * 16 + sRow) * ldb + kt, Bs + chunk * 512);
    }
    __syncthreads();

    s8v av[FM], bv[FN];
#pragma unroll
    for (int m = 0; m < FM; ++m)
      av[m] = *reinterpret_cast<const s8v*>(&As[(wm * (BM / 2) + m * 16 + fr) * 32 + koSw]);
#pragma unroll
    for (int n = 0; n < FN; ++n)
      bv[n] = *reinterpret_cast<const s8v*>(&Bs[(wn * (BN / 2) + n * 16 + fr) * 32 + koSw]);
#pragma unroll
    for (int m = 0; m < FM; ++m)
#pragma unroll
      for (int n = 0; n < FN; ++n)
        acc[m][n] = __builtin_amdgcn_mfma_f32_16x16x32_bf16(av[m], bv[n], acc[m][n], 0, 0, 0);
  }

  // ---------------- epilogue ----------------
  const int cr = (lane >> 4) * 4;  // row base within fragment
  const int cc = lane & 15;        // col within fragment

  int gcn[FN];
  float bcol[FN];
#pragma unroll
  for (int n = 0; n < FN; ++n) {
    gcn[n] = colBase + wn * (BN / 2) + n * 16 + cc;
    bcol[n] = (MODE == 3) ? 0.f : bias[gcn[n]];
  }

  if (MODE == 0 || MODE == 2) {
#pragma unroll
    for (int m = 0; m < FM; ++m)
#pragma unroll
      for (int r = 0; r < 4; ++r) {
        int gr = rowBase + wm * (BM / 2) + m * 16 + cr + r;
        float aw = 1.f;
        if (MODE == 2) aw = attn[gr * NE + eg];
#pragma unroll
        for (int n = 0; n < FN; ++n) {
          float v = acc[m][n][r] + bcol[n];
          if (relu) v = fmaxf(v, 0.f);
          if (MODE == 2) v *= aw;
          outB[(size_t)gr * ldo + gcn[n]] = f2bf(v);
        }
      }
  }

  if (MODE == 1) {
#pragma unroll
    for (int m = 0; m < FM; ++m)
#pragma unroll
      for (int r = 0; r < 4; ++r) {
        int gr = rowBase + wm * (BM / 2) + m * 16 + cr + r;
        int t = task[gr];
        const float* qrow = qk1 + (size_t)t * DH;
        float s = 0.f;
#pragma unroll
        for (int n = 0; n < FN; ++n) {
          float v = fmaxf(acc[m][n][r] + bcol[n], 0.f);
          s += v * qrow[gcn[n]];
        }
#pragma unroll
        for (int off = 1; off < 16; off <<= 1) s += __shfl_xor(s, off, 64);
        if (cc == 0) atomicAdd(&logits[gr * NE + eg], s);
      }
  }

  if (MODE == 3) {
#pragma unroll
    for (int m = 0; m < FM; ++m)
#pragma unroll
      for (int r = 0; r < 4; ++r) {
        int gr = rowBase + wm * (BM / 2) + m * 16 + cr + r;
#pragma unroll
        for (int n = 0; n < FN; ++n) {
          float v = acc[m][n][r] + cio[(size_t)gr * DK + gcn[n]];
          if (outBf) outB[(size_t)gr * DK + gcn[n]] = f2bf(v);
          else       cio[(size_t)gr * DK + gcn[n]] = v;
        }
      }
  }
}

// ---------------------------------------------------------------------------
// small kernels
// ---------------------------------------------------------------------------
__global__ void task_k(const float* __restrict__ state, int* __restrict__ task) {
  int b = blockIdx.x * blockDim.x + threadIdx.x;
  if (b >= NB) return;
  const float* p = state + (size_t)b * SLD + OBS;
  float best = p[0]; int bi = 0;
  for (int j = 1; j < NT; ++j) { float v = p[j]; if (v > best) { best = v; bi = j; } }
  task[b] = bi;
}

__global__ void buildx_k(const float* __restrict__ state, const float* __restrict__ act,
                         unsigned short* __restrict__ x) {
  int idx = blockIdx.x * blockDim.x + threadIdx.x;
  if (idx >= NB * XK) return;
  int b = idx / XK, j = idx - b * XK;
  float v = (j < OBS) ? state[(size_t)b * SLD + j] : act[(size_t)b * NACT + (j - OBS)];
  x[idx] = f2bf(v);
}

// block t: Qt[t,:] = tanh(emb[t,:]); qb[e,t] = Qt[t,:] . bk1[e,:]
__global__ void prep_emb_k(const float* __restrict__ emb, const float* __restrict__ bk1,
                           float* __restrict__ Qt, float* __restrict__ qb) {
  int t = blockIdx.x;
  __shared__ float qsh[DK];
  for (int k = threadIdx.x; k < DK; k += 256) {
    float v = tanhf(emb[t * DK + k]);
    Qt[t * DK + k] = v;
    qsh[k] = v;
  }
  __syncthreads();
  int wave = threadIdx.x >> 6, lane = threadIdx.x & 63;
  for (int e = wave; e < NE; e += 4) {
    float s = 0.f;
    for (int k = lane; k < DK; k += 64) s += qsh[k] * bk1[e * DK + k];
    for (int off = 1; off < 64; off <<= 1) s += __shfl_xor(s, off, 64);
    if (lane == 0) qb[e * NT + t] = s;
  }
}

// wave per (e,h): qk1[e,t,h] = sum_k Wk1[e,h,k] * Qt[t,k]
__global__ void qk1_k(const float* __restrict__ Wk1, const float* __restrict__ Qt,
                      float* __restrict__ qk1) {
  int w = (blockIdx.x * blockDim.x + threadIdx.x) >> 6;
  int lane = threadIdx.x & 63;
  if (w >= NE * DH) return;
  int e = w >> 10, h = w & (DH - 1);
  const float* wrow = Wk1 + ((size_t)e * DH + h) * DK + lane * 8;
  float wv[8];
#pragma unroll
  for (int j = 0; j < 8; ++j) wv[j] = wrow[j];
#pragma unroll
  for (int t = 0; t < NT; ++t) {
    const float* qrow = Qt + t * DK + lane * 8;
    float s = 0.f;
#pragma unroll
    for (int j = 0; j < 8; ++j) s += wv[j] * qrow[j];
#pragma unroll
    for (int off = 1; off < 64; off <<= 1) s += __shfl_xor(s, off, 64);
    if (lane == 0) qk1[((size_t)e * NT + t) * DH + h] = s;
  }
}

// transpose + fp32->bf16, 64x64 tile, coalesced float4 reads + 16B bf16 writes.
// dst[e*dBS + n*dLd + k] = bf16(src[e*sBS + k*N + n])
__global__ void __launch_bounds__(256)
convT_k(const float* __restrict__ src, unsigned short* __restrict__ dst,
        int N, long sBS, long dBS, int dLd) {
  __shared__ float tile[64][65];
  int e = blockIdx.z;
  int n0 = blockIdx.x * 64, k0 = blockIdx.y * 64;
  src += (size_t)e * sBS + (size_t)k0 * N + n0;
  dst += (size_t)e * dBS + (size_t)n0 * dLd + k0;
  int t = threadIdx.x;
  int c4 = t & 15, kr = t >> 4;            // 16 float4-cols x 16 rows per pass
#pragma unroll
  for (int i = 0; i < 4; ++i) {
    float4 v = *(const float4*)(src + (size_t)(kr + i * 16) * N + c4 * 4);
    tile[kr + i * 16][c4 * 4 + 0] = v.x;
    tile[kr + i * 16][c4 * 4 + 1] = v.y;
    tile[kr + i * 16][c4 * 4 + 2] = v.z;
    tile[kr + i * 16][c4 * 4 + 3] = v.w;
  }
  __syncthreads();
  int sub = t & 7, nl = t >> 3;            // 8 k-chunks x 32 n per pass
#pragma unroll
  for (int pass = 0; pass < 2; ++pass) {
    int n = nl + pass * 32;
    unsigned short v8[8];
#pragma unroll
    for (int j = 0; j < 8; ++j) v8[j] = f2bf(tile[sub * 8 + j][n]);
    *reinterpret_cast<s8v*>(dst + (size_t)n * dLd + sub * 8) =
        *reinterpret_cast<const s8v*>(v8);
  }
}

__global__ void softmax_k(const float* __restrict__ logits, const float* __restrict__ qb,
                          const int* __restrict__ task, float* __restrict__ attn,
                          float* __restrict__ lossOut) {
  int b = blockIdx.x * blockDim.x + threadIdx.x;
  int t = task[b];
  float l[NE];
  float mx = -1e30f;
#pragma unroll
  for (int e = 0; e < NE; ++e) { l[e] = logits[b * NE + e] + qb[e * NT + t]; mx = fmaxf(mx, l[e]); }
  float s = 0.f;
#pragma unroll
  for (int e = 0; e < NE; ++e) { l[e] = expf(l[e] - mx); s += l[e]; }
  float inv = 1.f / s;
  float loss = 0.f;
#pragma unroll
  for (int e = 0; e < NE; ++e) {
    float a = l[e] * inv;
    attn[b * NE + e] = a;
    float lg = logf(a + 1e-10f);
    loss += fminf(fmaxf(lg, -6.f), 0.f);
  }
  for (int off = 1; off < 64; off <<= 1) loss += __shfl_xor(loss, off, 64);
  if ((threadIdx.x & 63) == 0) atomicAdd(lossOut, loss * (-0.3f / NB));
}

// tower_in[b,k] = sum_e attn[b,e] * bv1[e,k]   (rank-16 init; also zero-fills)
__global__ void towerbias_k(const float* __restrict__ attn, const float* __restrict__ bv1,
                            float* __restrict__ towerin) {
  int idx = blockIdx.x * blockDim.x + threadIdx.x;
  if (idx >= NB * DK) return;
  int b = idx >> 9, k = idx & (DK - 1);
  float s = 0.f;
#pragma unroll
  for (int e = 0; e < NE; ++e) s += attn[b * NE + e] * bv1[e * DK + k];
  towerin[idx] = s;
}

// wave per row: q[b] = h2[b,:] . Wt2 + bt2
__global__ void qfinal_k(const unsigned short* __restrict__ h2, const float* __restrict__ Wt2,
                         const float* __restrict__ bt2, float* __restrict__ out) {
  int w = (blockIdx.x * blockDim.x + threadIdx.x) >> 6;
  int lane = threadIdx.x & 63;
  if (w >= NB) return;
  float s = 0.f;
#pragma unroll
  for (int j = 0; j < 4; ++j) {
    int k = lane * 4 + j;
    s += bf2f(h2[(size_t)w * 256 + k]) * Wt2[k];
  }
  for (int off = 1; off < 64; off <<= 1) s += __shfl_xor(s, off, 64);
  if (lane == 0) out[w] = s + bt2[0];
}

// ---------------------------------------------------------------------------
extern "C" void kernel_launch(void* const* d_in, const int* in_sizes, int n_in,
                              void* d_out, int out_size, void* d_ws, size_t ws_size,
                              hipStream_t stream) {
  const float* state  = (const float*)d_in[0];
  const float* act    = (const float*)d_in[1];
  const float* rep_W0 = (const float*)d_in[2];
  const float* rep_b0 = (const float*)d_in[3];
  const float* rep_W1 = (const float*)d_in[4];
  const float* rep_b1 = (const float*)d_in[5];
  const float* emb    = (const float*)d_in[6];
  const float* Wk0    = (const float*)d_in[7];
  const float* bk0    = (const float*)d_in[8];
  const float* Wk1    = (const float*)d_in[9];
  const float* bk1    = (const float*)d_in[10];
  const float* Wv0    = (const float*)d_in[11];
  const float* bv0    = (const float*)d_in[12];
  const float* Wv1    = (const float*)d_in[13];
  const float* bv1    = (const float*)d_in[14];
  const float* Wt0    = (const float*)d_in[15];
  const float* bt0    = (const float*)d_in[16];
  const float* Wt1    = (const float*)d_in[17];
  const float* bt1    = (const float*)d_in[18];
  const float* Wt2    = (const float*)d_in[19];
  const float* bt2    = (const float*)d_in[20];
  float* out = (float*)d_out;

  char* wsb = (char*)d_ws;
  size_t off = 0;
  auto alloc = [&](size_t bytes) -> void* {
    void* p = wsb + off;
    off += (bytes + 255) & ~(size_t)255;
    return p;
  };
  unsigned short* Ap    = (unsigned short*)alloc((size_t)NB * 8192 * 2);       // scaled hv, 8 experts
  unsigned short* Wk0t  = (unsigned short*)alloc((size_t)NE * DREP * DH * 2);
  unsigned short* Wv0t  = (unsigned short*)alloc((size_t)NE * DREP * DH * 2);
  unsigned short* Wv1t  = (unsigned short*)alloc((size_t)DK * (NE * DH) * 2);  // [n][e*1024+h]
  unsigned short* h0    = (unsigned short*)alloc((size_t)NB * DREP * 2);
  unsigned short* rep   = (unsigned short*)alloc((size_t)NB * DREP * 2);
  float*          twin  = (float*)alloc((size_t)NB * DK * 4);
  unsigned short* xbuf  = (unsigned short*)alloc((size_t)NB * XK * 2);
  unsigned short* ti    = (unsigned short*)alloc((size_t)NB * DK * 2);
  unsigned short* h1    = (unsigned short*)alloc((size_t)NB * 512 * 2);
  unsigned short* h2    = (unsigned short*)alloc((size_t)NB * 256 * 2);
  unsigned short* rW1t  = (unsigned short*)alloc((size_t)DREP * DREP * 2);
  unsigned short* rW0t  = (unsigned short*)alloc((size_t)DREP * XK * 2);
  float*          qk1   = (float*)alloc((size_t)NE * NT * DH * 4);
  unsigned short* Wt0t  = (unsigned short*)alloc((size_t)512 * 512 * 2);
  unsigned short* Wt1t  = (unsigned short*)alloc((size_t)256 * 512 * 2);
  float*          logits= (float*)alloc((size_t)NB * NE * 4);
  float*          attn  = (float*)alloc((size_t)NB * NE * 4);
  float*          Qt    = (float*)alloc((size_t)NT * DK * 4);
  int*            task  = (int*)alloc((size_t)NB * 4);
  float*          qb    = (float*)alloc((size_t)NE * NT * 4);

  hipMemsetAsync(logits, 0, (size_t)NB * NE * 4, stream);
  hipMemsetAsync(out + NB, 0, sizeof(float), stream);

  task_k<<<NB / 256, 256, 0, stream>>>(state, task);
  buildx_k<<<(NB * XK + 255) / 256, 256, 0, stream>>>(state, act, xbuf);
  prep_emb_k<<<NT, 256, 0, stream>>>(emb, bk1, Qt, qb);
  qk1_k<<<NE * DH / 4, 256, 0, stream>>>(Wk1, Qt, qk1);

  // transposes: grid (N/64, K/64, E)
  convT_k<<<dim3(DREP / 64, XK / 64, 1), 256, 0, stream>>>(rep_W0, rW0t, DREP, 0, 0, XK);
  convT_k<<<dim3(DREP / 64, DREP / 64, 1), 256, 0, stream>>>(rep_W1, rW1t, DREP, 0, 0, DREP);
  convT_k<<<dim3(DH / 64, DREP / 64, NE), 256, 0, stream>>>(Wk0, Wk0t, DH, (long)DREP * DH, (long)DREP * DH, DREP);
  convT_k<<<dim3(DH / 64, DREP / 64, NE), 256, 0, stream>>>(Wv0, Wv0t, DH, (long)DREP * DH, (long)DREP * DH, DREP);
  convT_k<<<dim3(DK / 64, DH / 64, NE), 256, 0, stream>>>(Wv1, Wv1t, DK, (long)DH * DK, 1024L, NE * DH);
  convT_k<<<dim3(512 / 64, 512 / 64, 1), 256, 0, stream>>>(Wt0, Wt0t, 512, 0, 0, 512);
  convT_k<<<dim3(256 / 64, 512 / 64, 1), 256, 0, stream>>>(Wt1, Wt1t, 256, 0, 0, 512);

  // rep MLP
  gemm_k<128, 128, 0><<<dim3(NB / 128, DREP / 128, 1), 256, 0, stream>>>(
      xbuf, XK, rW0t, XK, XK, rep_b0, 1, h0, DREP,
      nullptr, nullptr, nullptr, 0, nullptr, nullptr, 0);
  gemm_k<128, 128, 0><<<dim3(NB / 128, DREP / 128, 1), 256, 0, stream>>>(
      h0, DREP, rW1t, DREP, DREP, rep_b1, 0, rep, DREP,
      nullptr, nullptr, nullptr, 0, nullptr, nullptr, 0);

  // K-pass: hk fused into logits
  gemm_k<128, 128, 1><<<dim3(NB / 128, DH / 128, NE), 256, 0, stream>>>(
      rep, DREP, Wk0t, DREP, DREP, bk0, 1, nullptr, 0,
      qk1, task, logits, 0, nullptr, nullptr, 0);

  softmax_k<<<NB / 256, 256, 0, stream>>>(logits, qb, task, attn, out + NB);
  towerbias_k<<<NB * DK / 256, 256, 0, stream>>>(attn, bv1, twin);

  // V-pass + accumulate, 2 expert groups of 8
  for (int g = 0; g < 2; ++g) {
    gemm_k<128, 128, 2><<<dim3(NB / 128, DH / 128, 8), 256, 0, stream>>>(
        rep, DREP, Wv0t, DREP, DREP, bv0, 1, Ap, 8192,
        nullptr, nullptr, nullptr, g * 8, attn, nullptr, 0);
    gemm_k<64, 64, 3><<<dim3(NB / 64, DK / 64, 1), 256, 0, stream>>>(
        Ap, 8192, Wv1t + (size_t)g * 8192, NE * DH, 8192, nullptr, 0, ti, DK,
        nullptr, nullptr, nullptr, 0, nullptr, twin, g);  // g==1 -> write bf16 ti
  }

  // tower
  gemm_k<64, 64, 0><<<dim3(NB / 64, 512 / 64, 1), 256, 0, stream>>>(
      ti, DK, Wt0t, DK, DK, bt0, 1, h1, 512,
      nullptr, nullptr, nullptr, 0, nullptr, nullptr, 0);
  gemm_k<64, 64, 0><<<dim3(NB / 64, 256 / 64, 1), 256, 0, stream>>>(
      h1, 512, Wt1t, 512, 512, bt1, 1, h2, 256,
      nullptr, nullptr, nullptr, 0, nullptr, nullptr, 0);
  qfinal_k<<<NB / 4, 256, 0, stream>>>(h2, Wt2, bt2, out);
}

// Round 3
// 876.998 us; speedup vs baseline: 1.1106x; 1.1106x over previous
//
#include <hip/hip_runtime.h>
#include <cstdint>
#include <cstddef>

#define NB   4096
#define OBS  512
#define NACT 64
#define NT   10
#define NE   16
#define DREP 1024
#define DH   1024
#define DK   512
#define SLD  (OBS + NT)    // 522, state row length
#define XK   (OBS + NACT)  // 576

typedef short s8v __attribute__((ext_vector_type(8)));  // 8 bf16 in 4 VGPRs
typedef float f4v __attribute__((ext_vector_type(4)));

__device__ __forceinline__ unsigned short f2bf(float f) {
  union { float f; unsigned int u; } v; v.f = f;
  unsigned int u = v.u;
  unsigned int r = (u + 0x7FFFu + ((u >> 16) & 1u)) >> 16;  // RNE
  return (unsigned short)r;
}
__device__ __forceinline__ float bf2f(unsigned short h) {
  union { unsigned int u; float f; } v; v.u = ((unsigned int)h) << 16;
  return v.f;
}

__device__ __forceinline__ void gload_lds16(const unsigned short* gp, const unsigned short* lp) {
  __builtin_amdgcn_global_load_lds(
      (const __attribute__((address_space(1))) void*)(uintptr_t)gp,
      (__attribute__((address_space(3))) void*)(unsigned int)(uintptr_t)lp,
      16, 0, 0);
}

// ---------------------------------------------------------------------------
// Generic bf16 GEMM: C[M,N] = A[M,K] @ Bt[N,K]^T  (Bt is N-major, K contiguous)
// All dims compile-time (LDA/LDB/KK) so address math strength-reduces.
// LDS 16B chunks XOR-swizzled (slot s of row r holds k-chunk s ^ ((r>>1)&3));
// staging swizzles the per-lane GLOBAL k-offset, readers apply the same XOR.
// MODE 0: out = bf16(maybe_relu(C + bias[col]))
// MODE 1 (K-pass): v=relu(C+bk0[e,col]); atomicAdd logits[row,e] += v*qk1[e,task[row],col]
// MODE 2 (V-pass): out = bf16(attn[row,e] * relu(C + bv0[e,col])), e = eBase+blockIdx.z
// MODE 3 (split-K accum): blockIdx.z = K-chunk of size KK; atomicAdd fp32 into cio
// ---------------------------------------------------------------------------
template <int BM, int BN, int MODE, int RELU, int LDA, int LDB, int KK>
__global__ void __launch_bounds__(256)
gemm_k(const unsigned short* __restrict__ A,
       const unsigned short* __restrict__ Bt,
       const float* __restrict__ bias,
       unsigned short* __restrict__ outB, int ldo,
       const float* __restrict__ qk1, const int* __restrict__ task,
       float* __restrict__ logits, int eBase,
       const float* __restrict__ attn, float* __restrict__ cio)
{
  constexpr int FM = BM / 32;   // 16x16 frags per wave (M)
  constexpr int FN = BN / 32;
  constexpr int CA = BM / 64;   // 1KB staging chunks per wave (A)
  constexpr int CB = BN / 64;

  __shared__ __align__(16) unsigned short As[BM * 32];
  __shared__ __align__(16) unsigned short Bs[BN * 32];

  const int tid  = threadIdx.x;
  const int wave = tid >> 6;
  const int lane = tid & 63;
  const int wm = wave >> 1, wn = wave & 1;

  const int rowBase = blockIdx.x * BM;
  const int colBase = blockIdx.y * BN;

  int eg = 0;
  if (MODE == 1) {
    eg = blockIdx.z;
    Bt  += (size_t)eg * (DREP * DH);
    bias += eg * DH;
    qk1 += (size_t)eg * (NT * DH);
  }
  if (MODE == 2) {
    eg = eBase + blockIdx.z;
    Bt  += (size_t)eg * (DREP * DH);
    bias += eg * DH;
    outB += (size_t)blockIdx.z * DH;   // local slab in Ap
  }
  if (MODE == 3) {
    int kz = blockIdx.z;               // K-chunk
    A  += (size_t)kz * KK;
    Bt += (size_t)kz * KK;
  }

  f4v acc[FM][FN];
#pragma unroll
  for (int m = 0; m < FM; ++m)
#pragma unroll
    for (int n = 0; n < FN; ++n) acc[m][n] = f4v{0.f, 0.f, 0.f, 0.f};

  const int sRow = lane >> 2;                                 // row within 16-row chunk
  const int sSw  = ((lane & 3) ^ ((sRow >> 1) & 3)) * 8;      // swizzled global k-offset
  const unsigned short* Ag = A  + (size_t)rowBase * LDA + sSw;
  const unsigned short* Bg = Bt + (size_t)colBase * LDB + sSw;

  const int fr   = lane & 15;
  const int koSw = (((lane >> 4) ^ ((fr >> 1) & 3)) * 8);     // swizzled read slot

  for (int kt = 0; kt < KK; kt += 32) {
    __syncthreads();
#pragma unroll
    for (int j = 0; j < CA; ++j) {
      int chunk = wave * CA + j;
      gload_lds16(Ag + (size_t)(chunk * 16 + sRow) * LDA + kt, As + chunk * 512);
    }
#pragma unroll
    for (int j = 0; j < CB; ++j) {
      int chunk = wave * CB + j;
      gload_lds16(Bg + (size_t)(chunk * 16 + sRow) * LDB + kt, Bs + chunk * 512);
    }
    __syncthreads();

    s8v av[FM], bv[FN];
#pragma unroll
    for (int m = 0; m < FM; ++m)
      av[m] = *reinterpret_cast<const s8v*>(&As[(wm * (BM / 2) + m * 16 + fr) * 32 + koSw]);
#pragma unroll
    for (int n = 0; n < FN; ++n)
      bv[n] = *reinterpret_cast<const s8v*>(&Bs[(wn * (BN / 2) + n * 16 + fr) * 32 + koSw]);
#pragma unroll
    for (int m = 0; m < FM; ++m)
#pragma unroll
      for (int n = 0; n < FN; ++n)
        acc[m][n] = __builtin_amdgcn_mfma_f32_16x16x32_bf16(av[m], bv[n], acc[m][n], 0, 0, 0);
  }

  // ---------------- epilogue ----------------
  const int cr = (lane >> 4) * 4;  // row base within fragment
  const int cc = lane & 15;        // col within fragment

  int gcn[FN];
  float bcol[FN];
#pragma unroll
  for (int n = 0; n < FN; ++n) {
    gcn[n] = colBase + wn * (BN / 2) + n * 16 + cc;
    bcol[n] = (MODE == 3) ? 0.f : bias[gcn[n]];
  }

  if (MODE == 0 || MODE == 2) {
#pragma unroll
    for (int m = 0; m < FM; ++m)
#pragma unroll
      for (int r = 0; r < 4; ++r) {
        int gr = rowBase + wm * (BM / 2) + m * 16 + cr + r;
        float aw = 1.f;
        if (MODE == 2) aw = attn[gr * NE + eg];
#pragma unroll
        for (int n = 0; n < FN; ++n) {
          float v = acc[m][n][r] + bcol[n];
          if (RELU) v = fmaxf(v, 0.f);
          if (MODE == 2) v *= aw;
          outB[(size_t)gr * ldo + gcn[n]] = f2bf(v);
        }
      }
  }

  if (MODE == 1) {
#pragma unroll
    for (int m = 0; m < FM; ++m)
#pragma unroll
      for (int r = 0; r < 4; ++r) {
        int gr = rowBase + wm * (BM / 2) + m * 16 + cr + r;
        int t = task[gr];
        const float* qrow = qk1 + (size_t)t * DH;
        float s = 0.f;
#pragma unroll
        for (int n = 0; n < FN; ++n) {
          float v = fmaxf(acc[m][n][r] + bcol[n], 0.f);
          s += v * qrow[gcn[n]];
        }
#pragma unroll
        for (int off = 1; off < 16; off <<= 1) s += __shfl_xor(s, off, 64);
        if (cc == 0) atomicAdd(&logits[gr * NE + eg], s);
      }
  }

  if (MODE == 3) {
#pragma unroll
    for (int m = 0; m < FM; ++m)
#pragma unroll
      for (int r = 0; r < 4; ++r) {
        int gr = rowBase + wm * (BM / 2) + m * 16 + cr + r;
#pragma unroll
        for (int n = 0; n < FN; ++n)
          atomicAdd(&cio[(size_t)gr * DK + gcn[n]], acc[m][n][r]);
      }
  }
}

// ---------------------------------------------------------------------------
// small kernels
// ---------------------------------------------------------------------------
__global__ void task_k(const float* __restrict__ state, int* __restrict__ task) {
  int b = blockIdx.x * blockDim.x + threadIdx.x;
  if (b >= NB) return;
  const float* p = state + (size_t)b * SLD + OBS;
  float best = p[0]; int bi = 0;
  for (int j = 1; j < NT; ++j) { float v = p[j]; if (v > best) { best = v; bi = j; } }
  task[b] = bi;
}

__global__ void buildx_k(const float* __restrict__ state, const float* __restrict__ act,
                         unsigned short* __restrict__ x) {
  int idx = blockIdx.x * blockDim.x + threadIdx.x;
  if (idx >= NB * XK) return;
  int b = idx / XK, j = idx - b * XK;
  float v = (j < OBS) ? state[(size_t)b * SLD + j] : act[(size_t)b * NACT + (j - OBS)];
  x[idx] = f2bf(v);
}

// block t: Qt[t,:] = tanh(emb[t,:]); qb[e,t] = Qt[t,:] . bk1[e,:]
__global__ void prep_emb_k(const float* __restrict__ emb, const float* __restrict__ bk1,
                           float* __restrict__ Qt, float* __restrict__ qb) {
  int t = blockIdx.x;
  __shared__ float qsh[DK];
  for (int k = threadIdx.x; k < DK; k += 256) {
    float v = tanhf(emb[t * DK + k]);
    Qt[t * DK + k] = v;
    qsh[k] = v;
  }
  __syncthreads();
  int wave = threadIdx.x >> 6, lane = threadIdx.x & 63;
  for (int e = wave; e < NE; e += 4) {
    float s = 0.f;
    for (int k = lane; k < DK; k += 64) s += qsh[k] * bk1[e * DK + k];
    for (int off = 1; off < 64; off <<= 1) s += __shfl_xor(s, off, 64);
    if (lane == 0) qb[e * NT + t] = s;
  }
}

// wave per (e,h): qk1[e,t,h] = sum_k Wk1[e,h,k] * Qt[t,k]
__global__ void qk1_k(const float* __restrict__ Wk1, const float* __restrict__ Qt,
                      float* __restrict__ qk1) {
  int w = (blockIdx.x * blockDim.x + threadIdx.x) >> 6;
  int lane = threadIdx.x & 63;
  if (w >= NE * DH) return;
  int e = w >> 10, h = w & (DH - 1);
  const float* wrow = Wk1 + ((size_t)e * DH + h) * DK + lane * 8;
  float wv[8];
#pragma unroll
  for (int j = 0; j < 8; ++j) wv[j] = wrow[j];
#pragma unroll
  for (int t = 0; t < NT; ++t) {
    const float* qrow = Qt + t * DK + lane * 8;
    float s = 0.f;
#pragma unroll
    for (int j = 0; j < 8; ++j) s += wv[j] * qrow[j];
#pragma unroll
    for (int off = 1; off < 64; off <<= 1) s += __shfl_xor(s, off, 64);
    if (lane == 0) qk1[((size_t)e * NT + t) * DH + h] = s;
  }
}

// transpose + fp32->bf16, 64x64 tile, coalesced float4 reads + 16B bf16 writes.
// dst[e*dBS + n*dLd + k] = bf16(src[e*sBS + k*N + n])
__global__ void __launch_bounds__(256)
convT_k(const float* __restrict__ src, unsigned short* __restrict__ dst,
        int N, long sBS, long dBS, int dLd) {
  __shared__ float tile[64][65];
  int e = blockIdx.z;
  int n0 = blockIdx.x * 64, k0 = blockIdx.y * 64;
  src += (size_t)e * sBS + (size_t)k0 * N + n0;
  dst += (size_t)e * dBS + (size_t)n0 * dLd + k0;
  int t = threadIdx.x;
  int c4 = t & 15, kr = t >> 4;            // 16 float4-cols x 16 rows per pass
#pragma unroll
  for (int i = 0; i < 4; ++i) {
    float4 v = *(const float4*)(src + (size_t)(kr + i * 16) * N + c4 * 4);
    tile[kr + i * 16][c4 * 4 + 0] = v.x;
    tile[kr + i * 16][c4 * 4 + 1] = v.y;
    tile[kr + i * 16][c4 * 4 + 2] = v.z;
    tile[kr + i * 16][c4 * 4 + 3] = v.w;
  }
  __syncthreads();
  int sub = t & 7, nl = t >> 3;            // 8 k-chunks x 32 n per pass
#pragma unroll
  for (int pass = 0; pass < 2; ++pass) {
    int n = nl + pass * 32;
    unsigned short v8[8];
#pragma unroll
    for (int j = 0; j < 8; ++j) v8[j] = f2bf(tile[sub * 8 + j][n]);
    *reinterpret_cast<s8v*>(dst + (size_t)n * dLd + sub * 8) =
        *reinterpret_cast<const s8v*>(v8);
  }
}

__global__ void softmax_k(const float* __restrict__ logits, const float* __restrict__ qb,
                          const int* __restrict__ task, float* __restrict__ attn,
                          float* __restrict__ lossOut) {
  int b = blockIdx.x * blockDim.x + threadIdx.x;
  int t = task[b];
  float l[NE];
  float mx = -1e30f;
#pragma unroll
  for (int e = 0; e < NE; ++e) { l[e] = logits[b * NE + e] + qb[e * NT + t]; mx = fmaxf(mx, l[e]); }
  float s = 0.f;
#pragma unroll
  for (int e = 0; e < NE; ++e) { l[e] = expf(l[e] - mx); s += l[e]; }
  float inv = 1.f / s;
  float loss = 0.f;
#pragma unroll
  for (int e = 0; e < NE; ++e) {
    float a = l[e] * inv;
    attn[b * NE + e] = a;
    float lg = logf(a + 1e-10f);
    loss += fminf(fmaxf(lg, -6.f), 0.f);
  }
  for (int off = 1; off < 64; off <<= 1) loss += __shfl_xor(loss, off, 64);
  if ((threadIdx.x & 63) == 0) atomicAdd(lossOut, loss * (-0.3f / NB));
}

// tower_in[b,k] = sum_e attn[b,e] * bv1[e,k]   (rank-16 init for the accum atomics)
__global__ void towerbias_k(const float* __restrict__ attn, const float* __restrict__ bv1,
                            float* __restrict__ towerin) {
  int idx = blockIdx.x * blockDim.x + threadIdx.x;
  if (idx >= NB * DK) return;
  int b = idx >> 9, k = idx & (DK - 1);
  float s = 0.f;
#pragma unroll
  for (int e = 0; e < NE; ++e) s += attn[b * NE + e] * bv1[e * DK + k];
  towerin[idx] = s;
}

// ti = bf16(twin), 8 elems/thread
__global__ void cvt_ti_k(const float* __restrict__ twin, unsigned short* __restrict__ ti) {
  int idx = (blockIdx.x * blockDim.x + threadIdx.x) * 8;
  if (idx >= NB * DK) return;
  float4 a = *(const float4*)(twin + idx);
  float4 b = *(const float4*)(twin + idx + 4);
  unsigned short v8[8] = {f2bf(a.x), f2bf(a.y), f2bf(a.z), f2bf(a.w),
                          f2bf(b.x), f2bf(b.y), f2bf(b.z), f2bf(b.w)};
  *reinterpret_cast<s8v*>(ti + idx) = *reinterpret_cast<const s8v*>(v8);
}

// wave per row: q[b] = h2[b,:] . Wt2 + bt2
__global__ void qfinal_k(const unsigned short* __restrict__ h2, const float* __restrict__ Wt2,
                         const float* __restrict__ bt2, float* __restrict__ out) {
  int w = (blockIdx.x * blockDim.x + threadIdx.x) >> 6;
  int lane = threadIdx.x & 63;
  if (w >= NB) return;
  float s = 0.f;
#pragma unroll
  for (int j = 0; j < 4; ++j) {
    int k = lane * 4 + j;
    s += bf2f(h2[(size_t)w * 256 + k]) * Wt2[k];
  }
  for (int off = 1; off < 64; off <<= 1) s += __shfl_xor(s, off, 64);
  if (lane == 0) out[w] = s + bt2[0];
}

// ---------------------------------------------------------------------------
extern "C" void kernel_launch(void* const* d_in, const int* in_sizes, int n_in,
                              void* d_out, int out_size, void* d_ws, size_t ws_size,
                              hipStream_t stream) {
  const float* state  = (const float*)d_in[0];
  const float* act    = (const float*)d_in[1];
  const float* rep_W0 = (const float*)d_in[2];
  const float* rep_b0 = (const float*)d_in[3];
  const float* rep_W1 = (const float*)d_in[4];
  const float* rep_b1 = (const float*)d_in[5];
  const float* emb    = (const float*)d_in[6];
  const float* Wk0    = (const float*)d_in[7];
  const float* bk0    = (const float*)d_in[8];
  const float* Wk1    = (const float*)d_in[9];
  const float* bk1    = (const float*)d_in[10];
  const float* Wv0    = (const float*)d_in[11];
  const float* bv0    = (const float*)d_in[12];
  const float* Wv1    = (const float*)d_in[13];
  const float* bv1    = (const float*)d_in[14];
  const float* Wt0    = (const float*)d_in[15];
  const float* bt0    = (const float*)d_in[16];
  const float* Wt1    = (const float*)d_in[17];
  const float* bt1    = (const float*)d_in[18];
  const float* Wt2    = (const float*)d_in[19];
  const float* bt2    = (const float*)d_in[20];
  float* out = (float*)d_out;

  char* wsb = (char*)d_ws;
  size_t off = 0;
  auto alloc = [&](size_t bytes) -> void* {
    void* p = wsb + off;
    off += (bytes + 255) & ~(size_t)255;
    return p;
  };
  unsigned short* Ap    = (unsigned short*)alloc((size_t)NB * 8192 * 2);       // scaled hv, 8 experts
  unsigned short* Wk0t  = (unsigned short*)alloc((size_t)NE * DREP * DH * 2);
  unsigned short* Wv0t  = (unsigned short*)alloc((size_t)NE * DREP * DH * 2);
  unsigned short* Wv1t  = (unsigned short*)alloc((size_t)DK * (NE * DH) * 2);  // [n][e*1024+h]
  unsigned short* h0    = (unsigned short*)alloc((size_t)NB * DREP * 2);
  unsigned short* rep   = (unsigned short*)alloc((size_t)NB * DREP * 2);
  float*          twin  = (float*)alloc((size_t)NB * DK * 4);
  unsigned short* xbuf  = (unsigned short*)alloc((size_t)NB * XK * 2);
  unsigned short* ti    = (unsigned short*)alloc((size_t)NB * DK * 2);
  unsigned short* h1    = (unsigned short*)alloc((size_t)NB * 512 * 2);
  unsigned short* h2    = (unsigned short*)alloc((size_t)NB * 256 * 2);
  unsigned short* rW1t  = (unsigned short*)alloc((size_t)DREP * DREP * 2);
  unsigned short* rW0t  = (unsigned short*)alloc((size_t)DREP * XK * 2);
  float*          qk1   = (float*)alloc((size_t)NE * NT * DH * 4);
  unsigned short* Wt0t  = (unsigned short*)alloc((size_t)512 * 512 * 2);
  unsigned short* Wt1t  = (unsigned short*)alloc((size_t)256 * 512 * 2);
  float*          logits= (float*)alloc((size_t)NB * NE * 4);
  float*          attn  = (float*)alloc((size_t)NB * NE * 4);
  float*          Qt    = (float*)alloc((size_t)NT * DK * 4);
  int*            task  = (int*)alloc((size_t)NB * 4);
  float*          qb    = (float*)alloc((size_t)NE * NT * 4);

  hipMemsetAsync(logits, 0, (size_t)NB * NE * 4, stream);
  hipMemsetAsync(out + NB, 0, sizeof(float), stream);

  task_k<<<NB / 256, 256, 0, stream>>>(state, task);
  buildx_k<<<(NB * XK + 255) / 256, 256, 0, stream>>>(state, act, xbuf);
  prep_emb_k<<<NT, 256, 0, stream>>>(emb, bk1, Qt, qb);
  qk1_k<<<NE * DH / 4, 256, 0, stream>>>(Wk1, Qt, qk1);

  // transposes: grid (N/64, K/64, E)
  convT_k<<<dim3(DREP / 64, XK / 64, 1), 256, 0, stream>>>(rep_W0, rW0t, DREP, 0, 0, XK);
  convT_k<<<dim3(DREP / 64, DREP / 64, 1), 256, 0, stream>>>(rep_W1, rW1t, DREP, 0, 0, DREP);
  convT_k<<<dim3(DH / 64, DREP / 64, NE), 256, 0, stream>>>(Wk0, Wk0t, DH, (long)DREP * DH, (long)DREP * DH, DREP);
  convT_k<<<dim3(DH / 64, DREP / 64, NE), 256, 0, stream>>>(Wv0, Wv0t, DH, (long)DREP * DH, (long)DREP * DH, DREP);
  convT_k<<<dim3(DK / 64, DH / 64, NE), 256, 0, stream>>>(Wv1, Wv1t, DK, (long)DH * DK, 1024L, NE * DH);
  convT_k<<<dim3(512 / 64, 512 / 64, 1), 256, 0, stream>>>(Wt0, Wt0t, 512, 0, 0, 512);
  convT_k<<<dim3(256 / 64, 512 / 64, 1), 256, 0, stream>>>(Wt1, Wt1t, 256, 0, 0, 512);

  // rep MLP
  gemm_k<128, 128, 0, 1, XK, XK, XK><<<dim3(NB / 128, DREP / 128, 1), 256, 0, stream>>>(
      xbuf, rW0t, rep_b0, h0, DREP, nullptr, nullptr, nullptr, 0, nullptr, nullptr);
  gemm_k<128, 128, 0, 0, DREP, DREP, DREP><<<dim3(NB / 128, DREP / 128, 1), 256, 0, stream>>>(
      h0, rW1t, rep_b1, rep, DREP, nullptr, nullptr, nullptr, 0, nullptr, nullptr);

  // K-pass: hk fused into logits
  gemm_k<128, 128, 1, 1, DREP, DREP, DREP><<<dim3(NB / 128, DH / 128, NE), 256, 0, stream>>>(
      rep, Wk0t, bk0, nullptr, 0, qk1, task, logits, 0, nullptr, nullptr);

  softmax_k<<<NB / 256, 256, 0, stream>>>(logits, qb, task, attn, out + NB);
  towerbias_k<<<NB * DK / 256, 256, 0, stream>>>(attn, bv1, twin);

  // V-pass + split-K accumulate, 2 expert groups of 8
  for (int g = 0; g < 2; ++g) {
    gemm_k<128, 128, 2, 1, DREP, DREP, DREP><<<dim3(NB / 128, DH / 128, 8), 256, 0, stream>>>(
        rep, Wv0t, bv0, Ap, 8192, nullptr, nullptr, nullptr, g * 8, attn, nullptr);
    gemm_k<128, 128, 3, 0, 8192, NE * DH, 2048><<<dim3(NB / 128, DK / 128, 4), 256, 0, stream>>>(
        Ap, Wv1t + (size_t)g * 8192, nullptr, nullptr, 0,
        nullptr, nullptr, nullptr, 0, nullptr, twin);
  }
  cvt_ti_k<<<(NB * DK / 8 + 255) / 256, 256, 0, stream>>>(twin, ti);

  // tower
  gemm_k<64, 64, 0, 1, DK, DK, DK><<<dim3(NB / 64, 512 / 64, 1), 256, 0, stream>>>(
      ti, Wt0t, bt0, h1, 512, nullptr, nullptr, nullptr, 0, nullptr, nullptr);
  gemm_k<64, 64, 0, 1, 512, 512, 512><<<dim3(NB / 64, 256 / 64, 1), 256, 0, stream>>>(
      h1, Wt1t, bt1, h2, 256, nullptr, nullptr, nullptr, 0, nullptr, nullptr);
  qfinal_k<<<NB / 4, 256, 0, stream>>>(h2, Wt2, bt2, out);
}

// Round 4
// 841.719 us; speedup vs baseline: 1.1572x; 1.0419x over previous
//
#include <hip/hip_runtime.h>
#include <cstdint>
#include <cstddef>

#define NB   4096
#define OBS  512
#define NACT 64
#define NT   10
#define NE   16
#define DREP 1024
#define DH   1024
#define DK   512
#define SLD  (OBS + NT)    // 522, state row length
#define XK   (OBS + NACT)  // 576

typedef short s8v __attribute__((ext_vector_type(8)));  // 8 bf16 in 4 VGPRs
typedef float f4v __attribute__((ext_vector_type(4)));

__device__ __forceinline__ unsigned short f2bf(float f) {
  union { float f; unsigned int u; } v; v.f = f;
  unsigned int u = v.u;
  unsigned int r = (u + 0x7FFFu + ((u >> 16) & 1u)) >> 16;  // RNE
  return (unsigned short)r;
}
__device__ __forceinline__ float bf2f(unsigned short h) {
  union { unsigned int u; float f; } v; v.u = ((unsigned int)h) << 16;
  return v.f;
}

__device__ __forceinline__ void gload_lds16(const unsigned short* gp, const unsigned short* lp) {
  __builtin_amdgcn_global_load_lds(
      (const __attribute__((address_space(1))) void*)(uintptr_t)gp,
      (__attribute__((address_space(3))) void*)(unsigned int)(uintptr_t)lp,
      16, 0, 0);
}

// ---------------------------------------------------------------------------
// Generic bf16 GEMM: C[M,N] = A[M,K] @ Bt[N,K]^T  (Bt is N-major, K contiguous)
// Pipelined K-loop: double-buffered LDS; tile t+1 is issued AFTER barrier t and
// flies during compute of tile t (waited only at barrier t+1). One manual
// s_waitcnt(0)+s_barrier per iteration. Safe: at barrier t all waves finished
// compute t-1, so refilling buf[(t+1)&1] cannot race readers.
// LDS 16B chunks XOR-swizzled (slot s of row r holds k-chunk s ^ ((r>>1)&3)).
// MODE 0: out = bf16(maybe_relu(C + bias[col]))
// MODE 1 (K-pass): v=relu(C+bk0[e,col]); atomicAdd logits[row,e] += v*qk1[e,task[row],col]
// MODE 2 (V-pass): out = bf16(attn[row,e] * relu(C + bv0[e,col])), e = eBase+blockIdx.z
// MODE 3 (split-K partial write): P[z][row][col]  = C
// MODE 4 (split-K partial add):   P[z][row][col] += C
// ---------------------------------------------------------------------------
template <int BM, int BN, int MODE, int RELU, int LDA, int LDB, int KK>
__global__ void __launch_bounds__(256)
gemm_k(const unsigned short* __restrict__ A,
       const unsigned short* __restrict__ Bt,
       const float* __restrict__ bias,
       unsigned short* __restrict__ outB, int ldo,
       const float* __restrict__ qk1, const int* __restrict__ task,
       float* __restrict__ logits, int eBase,
       const float* __restrict__ attn, float* __restrict__ cio)
{
  constexpr int FM = BM / 32;   // 16x16 frags per wave (M)
  constexpr int FN = BN / 32;
  constexpr int CA = BM / 64;   // 1KB staging chunks per wave (A)
  constexpr int CB = BN / 64;
  constexpr int NTILES = KK / 32;

  __shared__ __align__(16) unsigned short As[2][BM * 32];
  __shared__ __align__(16) unsigned short Bs[2][BN * 32];

  const int tid  = threadIdx.x;
  const int wave = tid >> 6;
  const int lane = tid & 63;
  const int wm = wave >> 1, wn = wave & 1;

  const int rowBase = blockIdx.x * BM;
  const int colBase = blockIdx.y * BN;

  int eg = 0;
  if (MODE == 1) {
    eg = blockIdx.z;
    Bt  += (size_t)eg * (DREP * DH);
    bias += eg * DH;
    qk1 += (size_t)eg * (NT * DH);
  }
  if (MODE == 2) {
    eg = eBase + blockIdx.z;
    Bt  += (size_t)eg * (DREP * DH);
    bias += eg * DH;
    outB += (size_t)blockIdx.z * DH;   // local slab in Ap
  }
  if (MODE == 3 || MODE == 4) {
    A   += (size_t)blockIdx.z * KK;    // K-chunk
    Bt  += (size_t)blockIdx.z * KK;
    cio += (size_t)blockIdx.z * NB * DK;
  }

  f4v acc[FM][FN];
#pragma unroll
  for (int m = 0; m < FM; ++m)
#pragma unroll
    for (int n = 0; n < FN; ++n) acc[m][n] = f4v{0.f, 0.f, 0.f, 0.f};

  const int sRow = lane >> 2;                                 // row within 16-row chunk
  const int sSw  = ((lane & 3) ^ ((sRow >> 1) & 3)) * 8;      // swizzled global k-offset
  const unsigned short* Ag = A  + (size_t)rowBase * LDA + sSw;
  const unsigned short* Bg = Bt + (size_t)colBase * LDB + sSw;

  const int fr   = lane & 15;
  const int koSw = (((lane >> 4) ^ ((fr >> 1) & 3)) * 8);     // swizzled read slot

  // ---- prologue: stage tile 0 into buffer 0 ----
#pragma unroll
  for (int j = 0; j < CA; ++j) {
    int chunk = wave * CA + j;
    gload_lds16(Ag + (size_t)(chunk * 16 + sRow) * LDA, As[0] + chunk * 512);
  }
#pragma unroll
  for (int j = 0; j < CB; ++j) {
    int chunk = wave * CB + j;
    gload_lds16(Bg + (size_t)(chunk * 16 + sRow) * LDB, Bs[0] + chunk * 512);
  }

  for (int t = 0; t < NTILES; ++t) {
    const int buf = t & 1;
    __builtin_amdgcn_s_waitcnt(0);     // this wave's tile-t loads complete
    __builtin_amdgcn_s_barrier();      // => all waves' tile-t loads complete

    if (t + 1 < NTILES) {              // issue tile t+1; flies during compute
      const int kt = (t + 1) * 32;
#pragma unroll
      for (int j = 0; j < CA; ++j) {
        int chunk = wave * CA + j;
        gload_lds16(Ag + (size_t)(chunk * 16 + sRow) * LDA + kt, As[buf ^ 1] + chunk * 512);
      }
#pragma unroll
      for (int j = 0; j < CB; ++j) {
        int chunk = wave * CB + j;
        gload_lds16(Bg + (size_t)(chunk * 16 + sRow) * LDB + kt, Bs[buf ^ 1] + chunk * 512);
      }
    }

    s8v av[FM], bv[FN];
#pragma unroll
    for (int m = 0; m < FM; ++m)
      av[m] = *reinterpret_cast<const s8v*>(&As[buf][(wm * (BM / 2) + m * 16 + fr) * 32 + koSw]);
#pragma unroll
    for (int n = 0; n < FN; ++n)
      bv[n] = *reinterpret_cast<const s8v*>(&Bs[buf][(wn * (BN / 2) + n * 16 + fr) * 32 + koSw]);
#pragma unroll
    for (int m = 0; m < FM; ++m)
#pragma unroll
      for (int n = 0; n < FN; ++n)
        acc[m][n] = __builtin_amdgcn_mfma_f32_16x16x32_bf16(av[m], bv[n], acc[m][n], 0, 0, 0);
  }

  // ---------------- epilogue ----------------
  const int cr = (lane >> 4) * 4;  // row base within fragment
  const int cc = lane & 15;        // col within fragment

  int gcn[FN];
  float bcol[FN];
#pragma unroll
  for (int n = 0; n < FN; ++n) {
    gcn[n] = colBase + wn * (BN / 2) + n * 16 + cc;
    bcol[n] = (MODE >= 3) ? 0.f : bias[gcn[n]];
  }

  if (MODE == 0 || MODE == 2) {
#pragma unroll
    for (int m = 0; m < FM; ++m)
#pragma unroll
      for (int r = 0; r < 4; ++r) {
        int gr = rowBase + wm * (BM / 2) + m * 16 + cr + r;
        float aw = 1.f;
        if (MODE == 2) aw = attn[gr * NE + eg];
#pragma unroll
        for (int n = 0; n < FN; ++n) {
          float v = acc[m][n][r] + bcol[n];
          if (RELU) v = fmaxf(v, 0.f);
          if (MODE == 2) v *= aw;
          outB[(size_t)gr * ldo + gcn[n]] = f2bf(v);
        }
      }
  }

  if (MODE == 1) {
#pragma unroll
    for (int m = 0; m < FM; ++m)
#pragma unroll
      for (int r = 0; r < 4; ++r) {
        int gr = rowBase + wm * (BM / 2) + m * 16 + cr + r;
        int t = task[gr];
        const float* qrow = qk1 + (size_t)t * DH;
        float s = 0.f;
#pragma unroll
        for (int n = 0; n < FN; ++n) {
          float v = fmaxf(acc[m][n][r] + bcol[n], 0.f);
          s += v * qrow[gcn[n]];
        }
#pragma unroll
        for (int off = 1; off < 16; off <<= 1) s += __shfl_xor(s, off, 64);
        if (cc == 0) atomicAdd(&logits[gr * NE + eg], s);
      }
  }

  if (MODE == 3 || MODE == 4) {
#pragma unroll
    for (int m = 0; m < FM; ++m)
#pragma unroll
      for (int r = 0; r < 4; ++r) {
        int gr = rowBase + wm * (BM / 2) + m * 16 + cr + r;
#pragma unroll
        for (int n = 0; n < FN; ++n) {
          float v = acc[m][n][r];
          if (MODE == 4) v += cio[(size_t)gr * DK + gcn[n]];
          cio[(size_t)gr * DK + gcn[n]] = v;
        }
      }
  }
}

// ---------------------------------------------------------------------------
// small kernels
// ---------------------------------------------------------------------------
__global__ void task_k(const float* __restrict__ state, int* __restrict__ task) {
  int b = blockIdx.x * blockDim.x + threadIdx.x;
  if (b >= NB) return;
  const float* p = state + (size_t)b * SLD + OBS;
  float best = p[0]; int bi = 0;
  for (int j = 1; j < NT; ++j) { float v = p[j]; if (v > best) { best = v; bi = j; } }
  task[b] = bi;
}

__global__ void buildx_k(const float* __restrict__ state, const float* __restrict__ act,
                         unsigned short* __restrict__ x) {
  int idx = blockIdx.x * blockDim.x + threadIdx.x;
  if (idx >= NB * XK) return;
  int b = idx / XK, j = idx - b * XK;
  float v = (j < OBS) ? state[(size_t)b * SLD + j] : act[(size_t)b * NACT + (j - OBS)];
  x[idx] = f2bf(v);
}

// block t: Qt[t,:] = tanh(emb[t,:]); qb[e,t] = Qt[t,:] . bk1[e,:]
__global__ void prep_emb_k(const float* __restrict__ emb, const float* __restrict__ bk1,
                           float* __restrict__ Qt, float* __restrict__ qb) {
  int t = blockIdx.x;
  __shared__ float qsh[DK];
  for (int k = threadIdx.x; k < DK; k += 256) {
    float v = tanhf(emb[t * DK + k]);
    Qt[t * DK + k] = v;
    qsh[k] = v;
  }
  __syncthreads();
  int wave = threadIdx.x >> 6, lane = threadIdx.x & 63;
  for (int e = wave; e < NE; e += 4) {
    float s = 0.f;
    for (int k = lane; k < DK; k += 64) s += qsh[k] * bk1[e * DK + k];
    for (int off = 1; off < 64; off <<= 1) s += __shfl_xor(s, off, 64);
    if (lane == 0) qb[e * NT + t] = s;
  }
}

// wave per (e,h): qk1[e,t,h] = sum_k Wk1[e,h,k] * Qt[t,k]
__global__ void qk1_k(const float* __restrict__ Wk1, const float* __restrict__ Qt,
                      float* __restrict__ qk1) {
  int w = (blockIdx.x * blockDim.x + threadIdx.x) >> 6;
  int lane = threadIdx.x & 63;
  if (w >= NE * DH) return;
  int e = w >> 10, h = w & (DH - 1);
  const float* wrow = Wk1 + ((size_t)e * DH + h) * DK + lane * 8;
  float wv[8];
#pragma unroll
  for (int j = 0; j < 8; ++j) wv[j] = wrow[j];
#pragma unroll
  for (int t = 0; t < NT; ++t) {
    const float* qrow = Qt + t * DK + lane * 8;
    float s = 0.f;
#pragma unroll
    for (int j = 0; j < 8; ++j) s += wv[j] * qrow[j];
#pragma unroll
    for (int off = 1; off < 64; off <<= 1) s += __shfl_xor(s, off, 64);
    if (lane == 0) qk1[((size_t)e * NT + t) * DH + h] = s;
  }
}

// transpose + fp32->bf16, 64x64 tile, coalesced float4 reads + 16B bf16 writes.
// dst[e*dBS + n*dLd + k] = bf16(src[e*sBS + k*N + n])
__global__ void __launch_bounds__(256)
convT_k(const float* __restrict__ src, unsigned short* __restrict__ dst,
        int N, long sBS, long dBS, int dLd) {
  __shared__ float tile[64][65];
  int e = blockIdx.z;
  int n0 = blockIdx.x * 64, k0 = blockIdx.y * 64;
  src += (size_t)e * sBS + (size_t)k0 * N + n0;
  dst += (size_t)e * dBS + (size_t)n0 * dLd + k0;
  int t = threadIdx.x;
  int c4 = t & 15, kr = t >> 4;            // 16 float4-cols x 16 rows per pass
#pragma unroll
  for (int i = 0; i < 4; ++i) {
    float4 v = *(const float4*)(src + (size_t)(kr + i * 16) * N + c4 * 4);
    tile[kr + i * 16][c4 * 4 + 0] = v.x;
    tile[kr + i * 16][c4 * 4 + 1] = v.y;
    tile[kr + i * 16][c4 * 4 + 2] = v.z;
    tile[kr + i * 16][c4 * 4 + 3] = v.w;
  }
  __syncthreads();
  int sub = t & 7, nl = t >> 3;            // 8 k-chunks x 32 n per pass
#pragma unroll
  for (int pass = 0; pass < 2; ++pass) {
    int n = nl + pass * 32;
    unsigned short v8[8];
#pragma unroll
    for (int j = 0; j < 8; ++j) v8[j] = f2bf(tile[sub * 8 + j][n]);
    *reinterpret_cast<s8v*>(dst + (size_t)n * dLd + sub * 8) =
        *reinterpret_cast<const s8v*>(v8);
  }
}

__global__ void softmax_k(const float* __restrict__ logits, const float* __restrict__ qb,
                          const int* __restrict__ task, float* __restrict__ attn,
                          float* __restrict__ lossOut) {
  int b = blockIdx.x * blockDim.x + threadIdx.x;
  int t = task[b];
  float l[NE];
  float mx = -1e30f;
#pragma unroll
  for (int e = 0; e < NE; ++e) { l[e] = logits[b * NE + e] + qb[e * NT + t]; mx = fmaxf(mx, l[e]); }
  float s = 0.f;
#pragma unroll
  for (int e = 0; e < NE; ++e) { l[e] = expf(l[e] - mx); s += l[e]; }
  float inv = 1.f / s;
  float loss = 0.f;
#pragma unroll
  for (int e = 0; e < NE; ++e) {
    float a = l[e] * inv;
    attn[b * NE + e] = a;
    float lg = logf(a + 1e-10f);
    loss += fminf(fmaxf(lg, -6.f), 0.f);
  }
  for (int off = 1; off < 64; off <<= 1) loss += __shfl_xor(loss, off, 64);
  if ((threadIdx.x & 63) == 0) atomicAdd(lossOut, loss * (-0.3f / NB));
}

// tower_in[b,k] = sum_e attn[b,e] * bv1[e,k]   (rank-16 bias init)
__global__ void towerbias_k(const float* __restrict__ attn, const float* __restrict__ bv1,
                            float* __restrict__ towerin) {
  int idx = blockIdx.x * blockDim.x + threadIdx.x;
  if (idx >= NB * DK) return;
  int b = idx >> 9, k = idx & (DK - 1);
  float s = 0.f;
#pragma unroll
  for (int e = 0; e < NE; ++e) s += attn[b * NE + e] * bv1[e * DK + k];
  towerin[idx] = s;
}

// ti = bf16(twin + P0 + P1 + P2 + P3), 8 elems/thread
__global__ void cvt_ti_k(const float* __restrict__ twin, const float* __restrict__ P,
                         unsigned short* __restrict__ ti) {
  int idx = (blockIdx.x * blockDim.x + threadIdx.x) * 8;
  if (idx >= NB * DK) return;
  float v[8];
#pragma unroll
  for (int j = 0; j < 8; ++j) v[j] = twin[idx + j];
#pragma unroll
  for (int c = 0; c < 4; ++c) {
    const float* p = P + (size_t)c * NB * DK + idx;
#pragma unroll
    for (int j = 0; j < 8; ++j) v[j] += p[j];
  }
  unsigned short v8[8];
#pragma unroll
  for (int j = 0; j < 8; ++j) v8[j] = f2bf(v[j]);
  *reinterpret_cast<s8v*>(ti + idx) = *reinterpret_cast<const s8v*>(v8);
}

// wave per row: q[b] = h2[b,:] . Wt2 + bt2
__global__ void qfinal_k(const unsigned short* __restrict__ h2, const float* __restrict__ Wt2,
                         const float* __restrict__ bt2, float* __restrict__ out) {
  int w = (blockIdx.x * blockDim.x + threadIdx.x) >> 6;
  int lane = threadIdx.x & 63;
  if (w >= NB) return;
  float s = 0.f;
#pragma unroll
  for (int j = 0; j < 4; ++j) {
    int k = lane * 4 + j;
    s += bf2f(h2[(size_t)w * 256 + k]) * Wt2[k];
  }
  for (int off = 1; off < 64; off <<= 1) s += __shfl_xor(s, off, 64);
  if (lane == 0) out[w] = s + bt2[0];
}

// ---------------------------------------------------------------------------
extern "C" void kernel_launch(void* const* d_in, const int* in_sizes, int n_in,
                              void* d_out, int out_size, void* d_ws, size_t ws_size,
                              hipStream_t stream) {
  const float* state  = (const float*)d_in[0];
  const float* act    = (const float*)d_in[1];
  const float* rep_W0 = (const float*)d_in[2];
  const float* rep_b0 = (const float*)d_in[3];
  const float* rep_W1 = (const float*)d_in[4];
  const float* rep_b1 = (const float*)d_in[5];
  const float* emb    = (const float*)d_in[6];
  const float* Wk0    = (const float*)d_in[7];
  const float* bk0    = (const float*)d_in[8];
  const float* Wk1    = (const float*)d_in[9];
  const float* bk1    = (const float*)d_in[10];
  const float* Wv0    = (const float*)d_in[11];
  const float* bv0    = (const float*)d_in[12];
  const float* Wv1    = (const float*)d_in[13];
  const float* bv1    = (const float*)d_in[14];
  const float* Wt0    = (const float*)d_in[15];
  const float* bt0    = (const float*)d_in[16];
  const float* Wt1    = (const float*)d_in[17];
  const float* bt1    = (const float*)d_in[18];
  const float* Wt2    = (const float*)d_in[19];
  const float* bt2    = (const float*)d_in[20];
  float* out = (float*)d_out;

  char* wsb = (char*)d_ws;
  size_t off = 0;
  auto alloc = [&](size_t bytes) -> void* {
    void* p = wsb + off;
    off += (bytes + 255) & ~(size_t)255;
    return p;
  };
  unsigned short* Ap    = (unsigned short*)alloc((size_t)NB * 8192 * 2);       // scaled hv, 8 experts
  unsigned short* Wk0t  = (unsigned short*)alloc((size_t)NE * DREP * DH * 2);
  unsigned short* Wv0t  = (unsigned short*)alloc((size_t)NE * DREP * DH * 2);
  unsigned short* Wv1t  = (unsigned short*)alloc((size_t)DK * (NE * DH) * 2);  // [n][e*1024+h]
  float*          P     = (float*)alloc((size_t)4 * NB * DK * 4);              // split-K partials
  unsigned short* h0    = (unsigned short*)alloc((size_t)NB * DREP * 2);
  unsigned short* rep   = (unsigned short*)alloc((size_t)NB * DREP * 2);
  float*          twin  = (float*)alloc((size_t)NB * DK * 4);
  unsigned short* xbuf  = (unsigned short*)alloc((size_t)NB * XK * 2);
  unsigned short* ti    = (unsigned short*)alloc((size_t)NB * DK * 2);
  unsigned short* h1    = (unsigned short*)alloc((size_t)NB * 512 * 2);
  unsigned short* h2    = (unsigned short*)alloc((size_t)NB * 256 * 2);
  unsigned short* rW1t  = (unsigned short*)alloc((size_t)DREP * DREP * 2);
  unsigned short* rW0t  = (unsigned short*)alloc((size_t)DREP * XK * 2);
  float*          qk1   = (float*)alloc((size_t)NE * NT * DH * 4);
  unsigned short* Wt0t  = (unsigned short*)alloc((size_t)512 * 512 * 2);
  unsigned short* Wt1t  = (unsigned short*)alloc((size_t)256 * 512 * 2);
  float*          logits= (float*)alloc((size_t)NB * NE * 4);
  float*          attn  = (float*)alloc((size_t)NB * NE * 4);
  float*          Qt    = (float*)alloc((size_t)NT * DK * 4);
  int*            task  = (int*)alloc((size_t)NB * 4);
  float*          qb    = (float*)alloc((size_t)NE * NT * 4);

  hipMemsetAsync(logits, 0, (size_t)NB * NE * 4, stream);
  hipMemsetAsync(out + NB, 0, sizeof(float), stream);

  task_k<<<NB / 256, 256, 0, stream>>>(state, task);
  buildx_k<<<(NB * XK + 255) / 256, 256, 0, stream>>>(state, act, xbuf);
  prep_emb_k<<<NT, 256, 0, stream>>>(emb, bk1, Qt, qb);
  qk1_k<<<NE * DH / 4, 256, 0, stream>>>(Wk1, Qt, qk1);

  // transposes: grid (N/64, K/64, E)
  convT_k<<<dim3(DREP / 64, XK / 64, 1), 256, 0, stream>>>(rep_W0, rW0t, DREP, 0, 0, XK);
  convT_k<<<dim3(DREP / 64, DREP / 64, 1), 256, 0, stream>>>(rep_W1, rW1t, DREP, 0, 0, DREP);
  convT_k<<<dim3(DH / 64, DREP / 64, NE), 256, 0, stream>>>(Wk0, Wk0t, DH, (long)DREP * DH, (long)DREP * DH, DREP);
  convT_k<<<dim3(DH / 64, DREP / 64, NE), 256, 0, stream>>>(Wv0, Wv0t, DH, (long)DREP * DH, (long)DREP * DH, DREP);
  convT_k<<<dim3(DK / 64, DH / 64, NE), 256, 0, stream>>>(Wv1, Wv1t, DK, (long)DH * DK, 1024L, NE * DH);
  convT_k<<<dim3(512 / 64, 512 / 64, 1), 256, 0, stream>>>(Wt0, Wt0t, 512, 0, 0, 512);
  convT_k<<<dim3(256 / 64, 512 / 64, 1), 256, 0, stream>>>(Wt1, Wt1t, 256, 0, 0, 512);

  // rep MLP
  gemm_k<128, 128, 0, 1, XK, XK, XK><<<dim3(NB / 128, DREP / 128, 1), 256, 0, stream>>>(
      xbuf, rW0t, rep_b0, h0, DREP, nullptr, nullptr, nullptr, 0, nullptr, nullptr);
  gemm_k<128, 128, 0, 0, DREP, DREP, DREP><<<dim3(NB / 128, DREP / 128, 1), 256, 0, stream>>>(
      h0, rW1t, rep_b1, rep, DREP, nullptr, nullptr, nullptr, 0, nullptr, nullptr);

  // K-pass: hk fused into logits
  gemm_k<128, 128, 1, 1, DREP, DREP, DREP><<<dim3(NB / 128, DH / 128, NE), 256, 0, stream>>>(
      rep, Wk0t, bk0, nullptr, 0, qk1, task, logits, 0, nullptr, nullptr);

  softmax_k<<<NB / 256, 256, 0, stream>>>(logits, qb, task, attn, out + NB);
  towerbias_k<<<NB * DK / 256, 256, 0, stream>>>(attn, bv1, twin);

  // V-pass + split-K accumulate into per-chunk partials (race-free, no atomics)
  for (int g = 0; g < 2; ++g) {
    gemm_k<128, 128, 2, 1, DREP, DREP, DREP><<<dim3(NB / 128, DH / 128, 8), 256, 0, stream>>>(
        rep, Wv0t, bv0, Ap, 8192, nullptr, nullptr, nullptr, g * 8, attn, nullptr);
    if (g == 0)
      gemm_k<128, 128, 3, 0, 8192, NE * DH, 2048><<<dim3(NB / 128, DK / 128, 4), 256, 0, stream>>>(
          Ap, Wv1t, nullptr, nullptr, 0, nullptr, nullptr, nullptr, 0, nullptr, P);
    else
      gemm_k<128, 128, 4, 0, 8192, NE * DH, 2048><<<dim3(NB / 128, DK / 128, 4), 256, 0, stream>>>(
          Ap, Wv1t + (size_t)8192, nullptr, nullptr, 0, nullptr, nullptr, nullptr, 0, nullptr, P);
  }
  cvt_ti_k<<<(NB * DK / 8 + 255) / 256, 256, 0, stream>>>(twin, P, ti);

  // tower
  gemm_k<64, 64, 0, 1, DK, DK, DK><<<dim3(NB / 64, 512 / 64, 1), 256, 0, stream>>>(
      ti, Wt0t, bt0, h1, 512, nullptr, nullptr, nullptr, 0, nullptr, nullptr);
  gemm_k<64, 64, 0, 1, 512, 512, 512><<<dim3(NB / 64, 256 / 64, 1), 256, 0, stream>>>(
      h1, Wt1t, bt1, h2, 256, nullptr, nullptr, nullptr, 0, nullptr, nullptr);
  qfinal_k<<<NB / 4, 256, 0, stream>>>(h2, Wt2, bt2, out);
}

// Round 5
// 838.727 us; speedup vs baseline: 1.1613x; 1.0036x over previous
//
#include <hip/hip_runtime.h>
#include <cstdint>
#include <cstddef>

#define NB   4096
#define OBS  512
#define NACT 64
#define NT   10
#define NE   16
#define DREP 1024
#define DH   1024
#define DK   512
#define SLD  (OBS + NT)    // 522, state row length
#define XK   (OBS + NACT)  // 576

typedef short s8v __attribute__((ext_vector_type(8)));  // 8 bf16 in 4 VGPRs
typedef float f4v __attribute__((ext_vector_type(4)));

__device__ __forceinline__ unsigned short f2bf(float f) {
  union { float f; unsigned int u; } v; v.f = f;
  unsigned int u = v.u;
  unsigned int r = (u + 0x7FFFu + ((u >> 16) & 1u)) >> 16;  // RNE
  return (unsigned short)r;
}
__device__ __forceinline__ float bf2f(unsigned short h) {
  union { unsigned int u; float f; } v; v.u = ((unsigned int)h) << 16;
  return v.f;
}

__device__ __forceinline__ void gload_lds16(const unsigned short* gp, const unsigned short* lp) {
  __builtin_amdgcn_global_load_lds(
      (const __attribute__((address_space(1))) void*)(uintptr_t)gp,
      (__attribute__((address_space(3))) void*)(unsigned int)(uintptr_t)lp,
      16, 0, 0);
}

// ---------------------------------------------------------------------------
// Generic bf16 GEMM: C[M,N] = A[M,K] @ Bt[N,K]^T  (Bt is N-major, K contiguous)
// VALU-lean pipelined K-loop:
//  - unrolled by 2 => buffer index is compile-time, no dynamic buf math
//  - LDS read bases hoisted (frag offsets are ds_read imm offsets)
//  - staging via persistent pointers bumped +=32/tile
//  - dbuf LDS; tile t+1 issued after barrier t, flies during compute t
// LDS 16B chunks XOR-swizzled (slot s of row r holds k-chunk s ^ ((r>>1)&3)).
// MODE 0: out = bf16(maybe_relu(C + bias[col]))
// MODE 1 (K-pass): v=relu(C+bk0[e,col]); atomicAdd logits[row,e] += v*qk1[e,task[row],col]
// MODE 2 (V-pass): out = bf16(attn[row,e] * relu(C + bv0[e,col])), e = eBase+blockIdx.z
// MODE 3 (split-K partial write): P[z][row][col]  = C
// MODE 4 (split-K partial add):   P[z][row][col] += C
// ---------------------------------------------------------------------------
template <int BM, int BN, int MODE, int RELU, int LDA, int LDB, int KK>
__global__ void __launch_bounds__(256)
gemm_k(const unsigned short* __restrict__ A,
       const unsigned short* __restrict__ Bt,
       const float* __restrict__ bias,
       unsigned short* __restrict__ outB, int ldo,
       const float* __restrict__ qk1, const int* __restrict__ task,
       float* __restrict__ logits, int eBase,
       const float* __restrict__ attn, float* __restrict__ cio)
{
  constexpr int FM = BM / 32;   // 16x16 frags per wave (M)
  constexpr int FN = BN / 32;
  constexpr int CA = BM / 64;   // 1KB staging chunks per wave (A)
  constexpr int CB = BN / 64;
  constexpr int NTILES = KK / 32;
  static_assert((NTILES & 1) == 0, "K-loop unrolled by 2");

  __shared__ __align__(16) unsigned short As[2][BM * 32];
  __shared__ __align__(16) unsigned short Bs[2][BN * 32];

  const int tid  = threadIdx.x;
  const int wave = tid >> 6;
  const int lane = tid & 63;
  const int wm = wave >> 1, wn = wave & 1;

  const int rowBase = blockIdx.x * BM;
  const int colBase = blockIdx.y * BN;

  int eg = 0;
  if (MODE == 1) {
    eg = blockIdx.z;
    Bt  += (size_t)eg * (DREP * DH);
    bias += eg * DH;
    qk1 += (size_t)eg * (NT * DH);
  }
  if (MODE == 2) {
    eg = eBase + blockIdx.z;
    Bt  += (size_t)eg * (DREP * DH);
    bias += eg * DH;
    outB += (size_t)blockIdx.z * DH;   // local slab in Ap
  }
  if (MODE == 3 || MODE == 4) {
    A   += (size_t)blockIdx.z * KK;    // K-chunk
    Bt  += (size_t)blockIdx.z * KK;
    cio += (size_t)blockIdx.z * NB * DK;
  }

  f4v acc[FM][FN];
#pragma unroll
  for (int m = 0; m < FM; ++m)
#pragma unroll
    for (int n = 0; n < FN; ++n) acc[m][n] = f4v{0.f, 0.f, 0.f, 0.f};

  const int sRow = lane >> 2;                                 // row within 16-row chunk
  const int sSw  = ((lane & 3) ^ ((sRow >> 1) & 3)) * 8;      // swizzled global k-offset

  // persistent staging pointers, bumped +=32 per tile
  const unsigned short* ag[CA];
  const unsigned short* bg[CB];
#pragma unroll
  for (int j = 0; j < CA; ++j)
    ag[j] = A + (size_t)(rowBase + (wave * CA + j) * 16 + sRow) * LDA + sSw;
#pragma unroll
  for (int j = 0; j < CB; ++j)
    bg[j] = Bt + (size_t)(colBase + (wave * CB + j) * 16 + sRow) * LDB + sSw;

  // fixed LDS staging destinations
  unsigned short* asl[2][CA];
  unsigned short* bsl[2][CB];
#pragma unroll
  for (int b = 0; b < 2; ++b) {
#pragma unroll
    for (int j = 0; j < CA; ++j) asl[b][j] = &As[b][(wave * CA + j) * 512];
#pragma unroll
    for (int j = 0; j < CB; ++j) bsl[b][j] = &Bs[b][(wave * CB + j) * 512];
  }

  // hoisted LDS read bases; frag m/n offsets are m*512 elems (imm offsets)
  const int fr   = lane & 15;
  const int koSw = ((lane >> 4) ^ ((fr >> 1) & 3)) * 8;       // swizzled read slot
  const unsigned short* aRd[2] = { &As[0][(wm * (BM / 2) + fr) * 32 + koSw],
                                   &As[1][(wm * (BM / 2) + fr) * 32 + koSw] };
  const unsigned short* bRd[2] = { &Bs[0][(wn * (BN / 2) + fr) * 32 + koSw],
                                   &Bs[1][(wn * (BN / 2) + fr) * 32 + koSw] };

  auto stage = [&](int buf) {
#pragma unroll
    for (int j = 0; j < CA; ++j) { gload_lds16(ag[j], asl[buf][j]); ag[j] += 32; }
#pragma unroll
    for (int j = 0; j < CB; ++j) { gload_lds16(bg[j], bsl[buf][j]); bg[j] += 32; }
  };

  auto compute = [&](int buf) {
    s8v av[FM], bv[FN];
#pragma unroll
    for (int m = 0; m < FM; ++m)
      av[m] = *reinterpret_cast<const s8v*>(aRd[buf] + m * 512);
#pragma unroll
    for (int n = 0; n < FN; ++n)
      bv[n] = *reinterpret_cast<const s8v*>(bRd[buf] + n * 512);
#pragma unroll
    for (int m = 0; m < FM; ++m)
#pragma unroll
      for (int n = 0; n < FN; ++n)
        acc[m][n] = __builtin_amdgcn_mfma_f32_16x16x32_bf16(av[m], bv[n], acc[m][n], 0, 0, 0);
  };

  stage(0);  // prologue: tile 0 -> buf 0

  for (int t = 0; t < NTILES; t += 2) {
    __builtin_amdgcn_s_waitcnt(0);     // this wave's buf-0 loads complete
    __builtin_amdgcn_s_barrier();      // => all waves' buf-0 loads complete
    if (t + 1 < NTILES) stage(1);      // tile t+1 flies during compute t
    compute(0);

    __builtin_amdgcn_s_waitcnt(0);
    __builtin_amdgcn_s_barrier();
    if (t + 2 < NTILES) stage(0);
    compute(1);
  }

  // ---------------- epilogue ----------------
  const int cr = (lane >> 4) * 4;  // row base within fragment
  const int cc = lane & 15;        // col within fragment

  int gcn[FN];
  float bcol[FN];
#pragma unroll
  for (int n = 0; n < FN; ++n) {
    gcn[n] = colBase + wn * (BN / 2) + n * 16 + cc;
    bcol[n] = (MODE >= 3) ? 0.f : bias[gcn[n]];
  }

  if (MODE == 0 || MODE == 2) {
#pragma unroll
    for (int m = 0; m < FM; ++m)
#pragma unroll
      for (int r = 0; r < 4; ++r) {
        int gr = rowBase + wm * (BM / 2) + m * 16 + cr + r;
        float aw = 1.f;
        if (MODE == 2) aw = attn[gr * NE + eg];
#pragma unroll
        for (int n = 0; n < FN; ++n) {
          float v = acc[m][n][r] + bcol[n];
          if (RELU) v = fmaxf(v, 0.f);
          if (MODE == 2) v *= aw;
          outB[(size_t)gr * ldo + gcn[n]] = f2bf(v);
        }
      }
  }

  if (MODE == 1) {
#pragma unroll
    for (int m = 0; m < FM; ++m)
#pragma unroll
      for (int r = 0; r < 4; ++r) {
        int gr = rowBase + wm * (BM / 2) + m * 16 + cr + r;
        int tk = task[gr];
        const float* qrow = qk1 + (size_t)tk * DH;
        float s = 0.f;
#pragma unroll
        for (int n = 0; n < FN; ++n) {
          float v = fmaxf(acc[m][n][r] + bcol[n], 0.f);
          s += v * qrow[gcn[n]];
        }
#pragma unroll
        for (int off = 1; off < 16; off <<= 1) s += __shfl_xor(s, off, 64);
        if (cc == 0) atomicAdd(&logits[gr * NE + eg], s);
      }
  }

  if (MODE == 3 || MODE == 4) {
#pragma unroll
    for (int m = 0; m < FM; ++m)
#pragma unroll
      for (int r = 0; r < 4; ++r) {
        int gr = rowBase + wm * (BM / 2) + m * 16 + cr + r;
#pragma unroll
        for (int n = 0; n < FN; ++n) {
          float v = acc[m][n][r];
          if (MODE == 4) v += cio[(size_t)gr * DK + gcn[n]];
          cio[(size_t)gr * DK + gcn[n]] = v;
        }
      }
  }
}

// ---------------------------------------------------------------------------
// small kernels
// ---------------------------------------------------------------------------
__global__ void task_k(const float* __restrict__ state, int* __restrict__ task) {
  int b = blockIdx.x * blockDim.x + threadIdx.x;
  if (b >= NB) return;
  const float* p = state + (size_t)b * SLD + OBS;
  float best = p[0]; int bi = 0;
  for (int j = 1; j < NT; ++j) { float v = p[j]; if (v > best) { best = v; bi = j; } }
  task[b] = bi;
}

__global__ void buildx_k(const float* __restrict__ state, const float* __restrict__ act,
                         unsigned short* __restrict__ x) {
  int idx = blockIdx.x * blockDim.x + threadIdx.x;
  if (idx >= NB * XK) return;
  int b = idx / XK, j = idx - b * XK;
  float v = (j < OBS) ? state[(size_t)b * SLD + j] : act[(size_t)b * NACT + (j - OBS)];
  x[idx] = f2bf(v);
}

// block t: Qt[t,:] = tanh(emb[t,:]); qb[e,t] = Qt[t,:] . bk1[e,:]
__global__ void prep_emb_k(const float* __restrict__ emb, const float* __restrict__ bk1,
                           float* __restrict__ Qt, float* __restrict__ qb) {
  int t = blockIdx.x;
  __shared__ float qsh[DK];
  for (int k = threadIdx.x; k < DK; k += 256) {
    float v = tanhf(emb[t * DK + k]);
    Qt[t * DK + k] = v;
    qsh[k] = v;
  }
  __syncthreads();
  int wave = threadIdx.x >> 6, lane = threadIdx.x & 63;
  for (int e = wave; e < NE; e += 4) {
    float s = 0.f;
    for (int k = lane; k < DK; k += 64) s += qsh[k] * bk1[e * DK + k];
    for (int off = 1; off < 64; off <<= 1) s += __shfl_xor(s, off, 64);
    if (lane == 0) qb[e * NT + t] = s;
  }
}

// wave per (e,h): qk1[e,t,h] = sum_k Wk1[e,h,k] * Qt[t,k]
__global__ void qk1_k(const float* __restrict__ Wk1, const float* __restrict__ Qt,
                      float* __restrict__ qk1) {
  int w = (blockIdx.x * blockDim.x + threadIdx.x) >> 6;
  int lane = threadIdx.x & 63;
  if (w >= NE * DH) return;
  int e = w >> 10, h = w & (DH - 1);
  const float* wrow = Wk1 + ((size_t)e * DH + h) * DK + lane * 8;
  float wv[8];
#pragma unroll
  for (int j = 0; j < 8; ++j) wv[j] = wrow[j];
#pragma unroll
  for (int t = 0; t < NT; ++t) {
    const float* qrow = Qt + t * DK + lane * 8;
    float s = 0.f;
#pragma unroll
    for (int j = 0; j < 8; ++j) s += wv[j] * qrow[j];
#pragma unroll
    for (int off = 1; off < 64; off <<= 1) s += __shfl_xor(s, off, 64);
    if (lane == 0) qk1[((size_t)e * NT + t) * DH + h] = s;
  }
}

// transpose + fp32->bf16, 64x64 tile, coalesced float4 reads + 16B bf16 writes.
// dst[e*dBS + n*dLd + k] = bf16(src[e*sBS + k*N + n])
__global__ void __launch_bounds__(256)
convT_k(const float* __restrict__ src, unsigned short* __restrict__ dst,
        int N, long sBS, long dBS, int dLd) {
  __shared__ float tile[64][65];
  int e = blockIdx.z;
  int n0 = blockIdx.x * 64, k0 = blockIdx.y * 64;
  src += (size_t)e * sBS + (size_t)k0 * N + n0;
  dst += (size_t)e * dBS + (size_t)n0 * dLd + k0;
  int t = threadIdx.x;
  int c4 = t & 15, kr = t >> 4;            // 16 float4-cols x 16 rows per pass
#pragma unroll
  for (int i = 0; i < 4; ++i) {
    float4 v = *(const float4*)(src + (size_t)(kr + i * 16) * N + c4 * 4);
    tile[kr + i * 16][c4 * 4 + 0] = v.x;
    tile[kr + i * 16][c4 * 4 + 1] = v.y;
    tile[kr + i * 16][c4 * 4 + 2] = v.z;
    tile[kr + i * 16][c4 * 4 + 3] = v.w;
  }
  __syncthreads();
  int sub = t & 7, nl = t >> 3;            // 8 k-chunks x 32 n per pass
#pragma unroll
  for (int pass = 0; pass < 2; ++pass) {
    int n = nl + pass * 32;
    unsigned short v8[8];
#pragma unroll
    for (int j = 0; j < 8; ++j) v8[j] = f2bf(tile[sub * 8 + j][n]);
    *reinterpret_cast<s8v*>(dst + (size_t)n * dLd + sub * 8) =
        *reinterpret_cast<const s8v*>(v8);
  }
}

__global__ void softmax_k(const float* __restrict__ logits, const float* __restrict__ qb,
                          const int* __restrict__ task, float* __restrict__ attn,
                          float* __restrict__ lossOut) {
  int b = blockIdx.x * blockDim.x + threadIdx.x;
  int t = task[b];
  float l[NE];
  float mx = -1e30f;
#pragma unroll
  for (int e = 0; e < NE; ++e) { l[e] = logits[b * NE + e] + qb[e * NT + t]; mx = fmaxf(mx, l[e]); }
  float s = 0.f;
#pragma unroll
  for (int e = 0; e < NE; ++e) { l[e] = expf(l[e] - mx); s += l[e]; }
  float inv = 1.f / s;
  float loss = 0.f;
#pragma unroll
  for (int e = 0; e < NE; ++e) {
    float a = l[e] * inv;
    attn[b * NE + e] = a;
    float lg = logf(a + 1e-10f);
    loss += fminf(fmaxf(lg, -6.f), 0.f);
  }
  for (int off = 1; off < 64; off <<= 1) loss += __shfl_xor(loss, off, 64);
  if ((threadIdx.x & 63) == 0) atomicAdd(lossOut, loss * (-0.3f / NB));
}

// tower_in[b,k] = sum_e attn[b,e] * bv1[e,k]   (rank-16 bias init)
__global__ void towerbias_k(const float* __restrict__ attn, const float* __restrict__ bv1,
                            float* __restrict__ towerin) {
  int idx = blockIdx.x * blockDim.x + threadIdx.x;
  if (idx >= NB * DK) return;
  int b = idx >> 9, k = idx & (DK - 1);
  float s = 0.f;
#pragma unroll
  for (int e = 0; e < NE; ++e) s += attn[b * NE + e] * bv1[e * DK + k];
  towerin[idx] = s;
}

// ti = bf16(twin + P0 + P1 + P2 + P3), 8 elems/thread
__global__ void cvt_ti_k(const float* __restrict__ twin, const float* __restrict__ P,
                         unsigned short* __restrict__ ti) {
  int idx = (blockIdx.x * blockDim.x + threadIdx.x) * 8;
  if (idx >= NB * DK) return;
  float v[8];
#pragma unroll
  for (int j = 0; j < 8; ++j) v[j] = twin[idx + j];
#pragma unroll
  for (int c = 0; c < 4; ++c) {
    const float* p = P + (size_t)c * NB * DK + idx;
#pragma unroll
    for (int j = 0; j < 8; ++j) v[j] += p[j];
  }
  unsigned short v8[8];
#pragma unroll
  for (int j = 0; j < 8; ++j) v8[j] = f2bf(v[j]);
  *reinterpret_cast<s8v*>(ti + idx) = *reinterpret_cast<const s8v*>(v8);
}

// wave per row: q[b] = h2[b,:] . Wt2 + bt2
__global__ void qfinal_k(const unsigned short* __restrict__ h2, const float* __restrict__ Wt2,
                         const float* __restrict__ bt2, float* __restrict__ out) {
  int w = (blockIdx.x * blockDim.x + threadIdx.x) >> 6;
  int lane = threadIdx.x & 63;
  if (w >= NB) return;
  float s = 0.f;
#pragma unroll
  for (int j = 0; j < 4; ++j) {
    int k = lane * 4 + j;
    s += bf2f(h2[(size_t)w * 256 + k]) * Wt2[k];
  }
  for (int off = 1; off < 64; off <<= 1) s += __shfl_xor(s, off, 64);
  if (lane == 0) out[w] = s + bt2[0];
}

// ---------------------------------------------------------------------------
extern "C" void kernel_launch(void* const* d_in, const int* in_sizes, int n_in,
                              void* d_out, int out_size, void* d_ws, size_t ws_size,
                              hipStream_t stream) {
  const float* state  = (const float*)d_in[0];
  const float* act    = (const float*)d_in[1];
  const float* rep_W0 = (const float*)d_in[2];
  const float* rep_b0 = (const float*)d_in[3];
  const float* rep_W1 = (const float*)d_in[4];
  const float* rep_b1 = (const float*)d_in[5];
  const float* emb    = (const float*)d_in[6];
  const float* Wk0    = (const float*)d_in[7];
  const float* bk0    = (const float*)d_in[8];
  const float* Wk1    = (const float*)d_in[9];
  const float* bk1    = (const float*)d_in[10];
  const float* Wv0    = (const float*)d_in[11];
  const float* bv0    = (const float*)d_in[12];
  const float* Wv1    = (const float*)d_in[13];
  const float* bv1    = (const float*)d_in[14];
  const float* Wt0    = (const float*)d_in[15];
  const float* bt0    = (const float*)d_in[16];
  const float* Wt1    = (const float*)d_in[17];
  const float* bt1    = (const float*)d_in[18];
  const float* Wt2    = (const float*)d_in[19];
  const float* bt2    = (const float*)d_in[20];
  float* out = (float*)d_out;

  char* wsb = (char*)d_ws;
  size_t off = 0;
  auto alloc = [&](size_t bytes) -> void* {
    void* p = wsb + off;
    off += (bytes + 255) & ~(size_t)255;
    return p;
  };
  unsigned short* Ap    = (unsigned short*)alloc((size_t)NB * 8192 * 2);       // scaled hv, 8 experts
  unsigned short* Wk0t  = (unsigned short*)alloc((size_t)NE * DREP * DH * 2);
  unsigned short* Wv0t  = (unsigned short*)alloc((size_t)NE * DREP * DH * 2);
  unsigned short* Wv1t  = (unsigned short*)alloc((size_t)DK * (NE * DH) * 2);  // [n][e*1024+h]
  float*          P     = (float*)alloc((size_t)4 * NB * DK * 4);              // split-K partials
  unsigned short* h0    = (unsigned short*)alloc((size_t)NB * DREP * 2);
  unsigned short* rep   = (unsigned short*)alloc((size_t)NB * DREP * 2);
  float*          twin  = (float*)alloc((size_t)NB * DK * 4);
  unsigned short* xbuf  = (unsigned short*)alloc((size_t)NB * XK * 2);
  unsigned short* ti    = (unsigned short*)alloc((size_t)NB * DK * 2);
  unsigned short* h1    = (unsigned short*)alloc((size_t)NB * 512 * 2);
  unsigned short* h2    = (unsigned short*)alloc((size_t)NB * 256 * 2);
  unsigned short* rW1t  = (unsigned short*)alloc((size_t)DREP * DREP * 2);
  unsigned short* rW0t  = (unsigned short*)alloc((size_t)DREP * XK * 2);
  float*          qk1   = (float*)alloc((size_t)NE * NT * DH * 4);
  unsigned short* Wt0t  = (unsigned short*)alloc((size_t)512 * 512 * 2);
  unsigned short* Wt1t  = (unsigned short*)alloc((size_t)256 * 512 * 2);
  float*          logits= (float*)alloc((size_t)NB * NE * 4);
  float*          attn  = (float*)alloc((size_t)NB * NE * 4);
  float*          Qt    = (float*)alloc((size_t)NT * DK * 4);
  int*            task  = (int*)alloc((size_t)NB * 4);
  float*          qb    = (float*)alloc((size_t)NE * NT * 4);

  hipMemsetAsync(logits, 0, (size_t)NB * NE * 4, stream);
  hipMemsetAsync(out + NB, 0, sizeof(float), stream);

  task_k<<<NB / 256, 256, 0, stream>>>(state, task);
  buildx_k<<<(NB * XK + 255) / 256, 256, 0, stream>>>(state, act, xbuf);
  prep_emb_k<<<NT, 256, 0, stream>>>(emb, bk1, Qt, qb);
  qk1_k<<<NE * DH / 4, 256, 0, stream>>>(Wk1, Qt, qk1);

  // transposes: grid (N/64, K/64, E)
  convT_k<<<dim3(DREP / 64, XK / 64, 1), 256, 0, stream>>>(rep_W0, rW0t, DREP, 0, 0, XK);
  convT_k<<<dim3(DREP / 64, DREP / 64, 1), 256, 0, stream>>>(rep_W1, rW1t, DREP, 0, 0, DREP);
  convT_k<<<dim3(DH / 64, DREP / 64, NE), 256, 0, stream>>>(Wk0, Wk0t, DH, (long)DREP * DH, (long)DREP * DH, DREP);
  convT_k<<<dim3(DH / 64, DREP / 64, NE), 256, 0, stream>>>(Wv0, Wv0t, DH, (long)DREP * DH, (long)DREP * DH, DREP);
  convT_k<<<dim3(DK / 64, DH / 64, NE), 256, 0, stream>>>(Wv1, Wv1t, DK, (long)DH * DK, 1024L, NE * DH);
  convT_k<<<dim3(512 / 64, 512 / 64, 1), 256, 0, stream>>>(Wt0, Wt0t, 512, 0, 0, 512);
  convT_k<<<dim3(256 / 64, 512 / 64, 1), 256, 0, stream>>>(Wt1, Wt1t, 256, 0, 0, 512);

  // rep MLP
  gemm_k<128, 128, 0, 1, XK, XK, XK><<<dim3(NB / 128, DREP / 128, 1), 256, 0, stream>>>(
      xbuf, rW0t, rep_b0, h0, DREP, nullptr, nullptr, nullptr, 0, nullptr, nullptr);
  gemm_k<128, 128, 0, 0, DREP, DREP, DREP><<<dim3(NB / 128, DREP / 128, 1), 256, 0, stream>>>(
      h0, rW1t, rep_b1, rep, DREP, nullptr, nullptr, nullptr, 0, nullptr, nullptr);

  // K-pass: hk fused into logits
  gemm_k<128, 128, 1, 1, DREP, DREP, DREP><<<dim3(NB / 128, DH / 128, NE), 256, 0, stream>>>(
      rep, Wk0t, bk0, nullptr, 0, qk1, task, logits, 0, nullptr, nullptr);

  softmax_k<<<NB / 256, 256, 0, stream>>>(logits, qb, task, attn, out + NB);
  towerbias_k<<<NB * DK / 256, 256, 0, stream>>>(attn, bv1, twin);

  // V-pass + split-K accumulate into per-chunk partials (race-free, no atomics)
  for (int g = 0; g < 2; ++g) {
    gemm_k<128, 128, 2, 1, DREP, DREP, DREP><<<dim3(NB / 128, DH / 128, 8), 256, 0, stream>>>(
        rep, Wv0t, bv0, Ap, 8192, nullptr, nullptr, nullptr, g * 8, attn, nullptr);
    if (g == 0)
      gemm_k<128, 128, 3, 0, 8192, NE * DH, 2048><<<dim3(NB / 128, DK / 128, 4), 256, 0, stream>>>(
          Ap, Wv1t, nullptr, nullptr, 0, nullptr, nullptr, nullptr, 0, nullptr, P);
    else
      gemm_k<128, 128, 4, 0, 8192, NE * DH, 2048><<<dim3(NB / 128, DK / 128, 4), 256, 0, stream>>>(
          Ap, Wv1t + (size_t)8192, nullptr, nullptr, 0, nullptr, nullptr, nullptr, 0, nullptr, P);
  }
  cvt_ti_k<<<(NB * DK / 8 + 255) / 256, 256, 0, stream>>>(twin, P, ti);

  // tower
  gemm_k<64, 64, 0, 1, DK, DK, DK><<<dim3(NB / 64, 512 / 64, 1), 256, 0, stream>>>(
      ti, Wt0t, bt0, h1, 512, nullptr, nullptr, nullptr, 0, nullptr, nullptr);
  gemm_k<64, 64, 0, 1, 512, 512, 512><<<dim3(NB / 64, 256 / 64, 1), 256, 0, stream>>>(
      h1, Wt1t, bt1, h2, 256, nullptr, nullptr, nullptr, 0, nullptr, nullptr);
  qfinal_k<<<NB / 4, 256, 0, stream>>>(h2, Wt2, bt2, out);
}

// Round 7
// 767.806 us; speedup vs baseline: 1.2686x; 1.0924x over previous
//
#include <hip/hip_runtime.h>
#include <cstdint>
#include <cstddef>

#define NB   4096
#define OBS  512
#define NACT 64
#define NT   10
#define NE   16
#define DREP 1024
#define DH   1024
#define DK   512
#define SLD  (OBS + NT)    // 522, state row length
#define XK   (OBS + NACT)  // 576

typedef short s8v __attribute__((ext_vector_type(8)));  // 8 bf16 in 4 VGPRs
typedef float f4v __attribute__((ext_vector_type(4)));

__device__ __forceinline__ unsigned short f2bf(float f) {
  union { float f; unsigned int u; } v; v.f = f;
  unsigned int u = v.u;
  unsigned int r = (u + 0x7FFFu + ((u >> 16) & 1u)) >> 16;  // RNE
  return (unsigned short)r;
}
__device__ __forceinline__ float bf2f(unsigned short h) {
  union { unsigned int u; float f; } v; v.u = ((unsigned int)h) << 16;
  return v.f;
}

__device__ __forceinline__ void gload_lds16(const unsigned short* gp, const unsigned short* lp) {
  __builtin_amdgcn_global_load_lds(
      (const __attribute__((address_space(1))) void*)(uintptr_t)gp,
      (__attribute__((address_space(3))) void*)(unsigned int)(uintptr_t)lp,
      16, 0, 0);
}

// ---------------------------------------------------------------------------
// Generic bf16 GEMM: C[M,N] = A[M,K] @ Bt[N,K]^T  (Bt is N-major, K contiguous)
// 3-stage pipelined K-loop (AITER-style): triple-buffered LDS, prefetch
// distance 2, mid-loop s_waitcnt vmcnt(LPS) where LPS = loads/stage (never 0),
// ONE barrier per tile.  vmcnt retires in order, so vmcnt(LPS) with 2 stages
// outstanding == "stage t complete, stage t+1 still flying".
// R6 bug fixed here: wait was hard-coded vmcnt(4); 64-tile kernels have LPS=2,
// so vmcnt(4) never waited -> read of unstaged LDS -> NaN.
// Buffer-reuse safety: at barrier t every wave consumed its buf-(t-1)%3
// ds_reads into registers (lgkm waits precede the tile-(t-1) MFMAs), so
// staging tile t+2 into that buffer after the barrier cannot race.
// LDS 16B chunks XOR-swizzled (slot s of row r holds k-chunk s ^ ((r>>1)&3)).
// MODE 0: out = bf16(maybe_relu(C + bias[col]))
// MODE 1 (K-pass): v=relu(C+bk0[e,col]); atomicAdd logits[row,e] += v*qk1[e,task[row],col]
// MODE 2 (V-pass): out = bf16(attn[row,e] * relu(C + bv0[e,col])), e = eBase+blockIdx.z
// MODE 3 (split-K partial write): P[z][row][col]  = C
// MODE 4 (split-K partial add):   P[z][row][col] += C
// ---------------------------------------------------------------------------
template <int BM, int BN, int MODE, int RELU, int LDA, int LDB, int KK>
__global__ void __launch_bounds__(256)
gemm_k(const unsigned short* __restrict__ A,
       const unsigned short* __restrict__ Bt,
       const float* __restrict__ bias,
       unsigned short* __restrict__ outB, int ldo,
       const float* __restrict__ qk1, const int* __restrict__ task,
       float* __restrict__ logits, int eBase,
       const float* __restrict__ attn, float* __restrict__ cio)
{
  constexpr int FM = BM / 32;   // 16x16 frags per wave (M)
  constexpr int FN = BN / 32;
  constexpr int CA = BM / 64;   // 1KB staging chunks per wave (A)
  constexpr int CB = BN / 64;
  constexpr int NTILES = KK / 32;
  static_assert(NTILES >= 3, "pipeline depth");
  constexpr int LPS = CA + CB;           // loads per stage per wave
  static_assert(LPS < 16, "vmcnt immediate fits in low bits");
  // s_waitcnt imm (gfx9): vmcnt[3:0], expcnt[6:4]=7, lgkmcnt[11:8]=0xF
  constexpr int WAIT_STAGE = 0xF70 | LPS;  // vmcnt(LPS): prev stage done
  constexpr int WAIT_ALL   = 0xF70;        // vmcnt(0): drain (tail only)

  __shared__ __align__(16) unsigned short As[3][BM * 32];
  __shared__ __align__(16) unsigned short Bs[3][BN * 32];

  const int tid  = threadIdx.x;
  const int wave = tid >> 6;
  const int lane = tid & 63;
  const int wm = wave >> 1, wn = wave & 1;

  const int rowBase = blockIdx.x * BM;
  const int colBase = blockIdx.y * BN;

  int eg = 0;
  if (MODE == 1) {
    eg = blockIdx.z;
    Bt  += (size_t)eg * (DREP * DH);
    bias += eg * DH;
    qk1 += (size_t)eg * (NT * DH);
  }
  if (MODE == 2) {
    eg = eBase + blockIdx.z;
    Bt  += (size_t)eg * (DREP * DH);
    bias += eg * DH;
    outB += (size_t)blockIdx.z * DH;   // local slab in Ap
  }
  if (MODE == 3 || MODE == 4) {
    A   += (size_t)blockIdx.z * KK;    // K-chunk
    Bt  += (size_t)blockIdx.z * KK;
    cio += (size_t)blockIdx.z * NB * DK;
  }

  f4v acc[FM][FN];
#pragma unroll
  for (int m = 0; m < FM; ++m)
#pragma unroll
    for (int n = 0; n < FN; ++n) acc[m][n] = f4v{0.f, 0.f, 0.f, 0.f};

  const int sRow = lane >> 2;                                 // row within 16-row chunk
  const int sSw  = ((lane & 3) ^ ((sRow >> 1) & 3)) * 8;      // swizzled global k-offset

  // persistent staging pointers, bumped +=32 per staged tile
  const unsigned short* ag[CA];
  const unsigned short* bg[CB];
#pragma unroll
  for (int j = 0; j < CA; ++j)
    ag[j] = A + (size_t)(rowBase + (wave * CA + j) * 16 + sRow) * LDA + sSw;
#pragma unroll
  for (int j = 0; j < CB; ++j)
    bg[j] = Bt + (size_t)(colBase + (wave * CB + j) * 16 + sRow) * LDB + sSw;

  const int fr   = lane & 15;
  const int koSw = ((lane >> 4) ^ ((fr >> 1) & 3)) * 8;       // swizzled read slot
  const int aOff = (wm * (BM / 2) + fr) * 32 + koSw;
  const int bOff = (wn * (BN / 2) + fr) * 32 + koSw;

  auto stage = [&](int buf) {
#pragma unroll
    for (int j = 0; j < CA; ++j) { gload_lds16(ag[j], &As[buf][(wave * CA + j) * 512]); ag[j] += 32; }
#pragma unroll
    for (int j = 0; j < CB; ++j) { gload_lds16(bg[j], &Bs[buf][(wave * CB + j) * 512]); bg[j] += 32; }
  };

  auto compute = [&](int buf) {
    s8v av[FM], bv[FN];
#pragma unroll
    for (int m = 0; m < FM; ++m)
      av[m] = *reinterpret_cast<const s8v*>(&As[buf][aOff + m * 512]);
#pragma unroll
    for (int n = 0; n < FN; ++n)
      bv[n] = *reinterpret_cast<const s8v*>(&Bs[buf][bOff + n * 512]);
#pragma unroll
    for (int m = 0; m < FM; ++m)
#pragma unroll
      for (int n = 0; n < FN; ++n)
        acc[m][n] = __builtin_amdgcn_mfma_f32_16x16x32_bf16(av[m], bv[n], acc[m][n], 0, 0, 0);
  };

  stage(0);   // tile 0
  stage(1);   // tile 1

  for (int t = 0; t < NTILES; t += 3) {
    // ---- tile t (buf 0) ----
    if (t + 1 < NTILES) __builtin_amdgcn_s_waitcnt(WAIT_STAGE);
    else                __builtin_amdgcn_s_waitcnt(WAIT_ALL);
    __builtin_amdgcn_s_barrier();
    if (t + 2 < NTILES) stage(2);
    compute(0);
    // ---- tile t+1 (buf 1) ----
    if (t + 1 < NTILES) {
      if (t + 2 < NTILES) __builtin_amdgcn_s_waitcnt(WAIT_STAGE);
      else                __builtin_amdgcn_s_waitcnt(WAIT_ALL);
      __builtin_amdgcn_s_barrier();
      if (t + 3 < NTILES) stage(0);
      compute(1);
    }
    // ---- tile t+2 (buf 2) ----
    if (t + 2 < NTILES) {
      if (t + 3 < NTILES) __builtin_amdgcn_s_waitcnt(WAIT_STAGE);
      else                __builtin_amdgcn_s_waitcnt(WAIT_ALL);
      __builtin_amdgcn_s_barrier();
      if (t + 4 < NTILES) stage(1);
      compute(2);
    }
  }

  // ---------------- epilogue ----------------
  const int cr = (lane >> 4) * 4;  // row base within fragment
  const int cc = lane & 15;        // col within fragment

  int gcn[FN];
  float bcol[FN];
#pragma unroll
  for (int n = 0; n < FN; ++n) {
    gcn[n] = colBase + wn * (BN / 2) + n * 16 + cc;
    bcol[n] = (MODE >= 3) ? 0.f : bias[gcn[n]];
  }

  if (MODE == 0 || MODE == 2) {
#pragma unroll
    for (int m = 0; m < FM; ++m)
#pragma unroll
      for (int r = 0; r < 4; ++r) {
        int gr = rowBase + wm * (BM / 2) + m * 16 + cr + r;
        float aw = 1.f;
        if (MODE == 2) aw = attn[gr * NE + eg];
#pragma unroll
        for (int n = 0; n < FN; ++n) {
          float v = acc[m][n][r] + bcol[n];
          if (RELU) v = fmaxf(v, 0.f);
          if (MODE == 2) v *= aw;
          outB[(size_t)gr * ldo + gcn[n]] = f2bf(v);
        }
      }
  }

  if (MODE == 1) {
#pragma unroll
    for (int m = 0; m < FM; ++m)
#pragma unroll
      for (int r = 0; r < 4; ++r) {
        int gr = rowBase + wm * (BM / 2) + m * 16 + cr + r;
        int tk = task[gr];
        const float* qrow = qk1 + (size_t)tk * DH;
        float s = 0.f;
#pragma unroll
        for (int n = 0; n < FN; ++n) {
          float v = fmaxf(acc[m][n][r] + bcol[n], 0.f);
          s += v * qrow[gcn[n]];
        }
#pragma unroll
        for (int off = 1; off < 16; off <<= 1) s += __shfl_xor(s, off, 64);
        if (cc == 0) atomicAdd(&logits[gr * NE + eg], s);
      }
  }

  if (MODE == 3 || MODE == 4) {
#pragma unroll
    for (int m = 0; m < FM; ++m)
#pragma unroll
      for (int r = 0; r < 4; ++r) {
        int gr = rowBase + wm * (BM / 2) + m * 16 + cr + r;
#pragma unroll
        for (int n = 0; n < FN; ++n) {
          float v = acc[m][n][r];
          if (MODE == 4) v += cio[(size_t)gr * DK + gcn[n]];
          cio[(size_t)gr * DK + gcn[n]] = v;
        }
      }
  }
}

// ---------------------------------------------------------------------------
// small kernels
// ---------------------------------------------------------------------------
__global__ void task_k(const float* __restrict__ state, int* __restrict__ task) {
  int b = blockIdx.x * blockDim.x + threadIdx.x;
  if (b >= NB) return;
  const float* p = state + (size_t)b * SLD + OBS;
  float best = p[0]; int bi = 0;
  for (int j = 1; j < NT; ++j) { float v = p[j]; if (v > best) { best = v; bi = j; } }
  task[b] = bi;
}

__global__ void buildx_k(const float* __restrict__ state, const float* __restrict__ act,
                         unsigned short* __restrict__ x) {
  int idx = blockIdx.x * blockDim.x + threadIdx.x;
  if (idx >= NB * XK) return;
  int b = idx / XK, j = idx - b * XK;
  float v = (j < OBS) ? state[(size_t)b * SLD + j] : act[(size_t)b * NACT + (j - OBS)];
  x[idx] = f2bf(v);
}

// block t: Qt[t,:] = tanh(emb[t,:]); qb[e,t] = Qt[t,:] . bk1[e,:]
__global__ void prep_emb_k(const float* __restrict__ emb, const float* __restrict__ bk1,
                           float* __restrict__ Qt, float* __restrict__ qb) {
  int t = blockIdx.x;
  __shared__ float qsh[DK];
  for (int k = threadIdx.x; k < DK; k += 256) {
    float v = tanhf(emb[t * DK + k]);
    Qt[t * DK + k] = v;
    qsh[k] = v;
  }
  __syncthreads();
  int wave = threadIdx.x >> 6, lane = threadIdx.x & 63;
  for (int e = wave; e < NE; e += 4) {
    float s = 0.f;
    for (int k = lane; k < DK; k += 64) s += qsh[k] * bk1[e * DK + k];
    for (int off = 1; off < 64; off <<= 1) s += __shfl_xor(s, off, 64);
    if (lane == 0) qb[e * NT + t] = s;
  }
}

// wave per (e,h): qk1[e,t,h] = sum_k Wk1[e,h,k] * Qt[t,k]
__global__ void qk1_k(const float* __restrict__ Wk1, const float* __restrict__ Qt,
                      float* __restrict__ qk1) {
  int w = (blockIdx.x * blockDim.x + threadIdx.x) >> 6;
  int lane = threadIdx.x & 63;
  if (w >= NE * DH) return;
  int e = w >> 10, h = w & (DH - 1);
  const float* wrow = Wk1 + ((size_t)e * DH + h) * DK + lane * 8;
  float wv[8];
#pragma unroll
  for (int j = 0; j < 8; ++j) wv[j] = wrow[j];
#pragma unroll
  for (int t = 0; t < NT; ++t) {
    const float* qrow = Qt + t * DK + lane * 8;
    float s = 0.f;
#pragma unroll
    for (int j = 0; j < 8; ++j) s += wv[j] * qrow[j];
#pragma unroll
    for (int off = 1; off < 64; off <<= 1) s += __shfl_xor(s, off, 64);
    if (lane == 0) qk1[((size_t)e * NT + t) * DH + h] = s;
  }
}

// transpose + fp32->bf16, 64x64 tile, coalesced float4 reads + 16B bf16 writes.
// dst[e*dBS + n*dLd + k] = bf16(src[e*sBS + k*N + n])
__global__ void __launch_bounds__(256)
convT_k(const float* __restrict__ src, unsigned short* __restrict__ dst,
        int N, long sBS, long dBS, int dLd) {
  __shared__ float tile[64][65];
  int e = blockIdx.z;
  int n0 = blockIdx.x * 64, k0 = blockIdx.y * 64;
  src += (size_t)e * sBS + (size_t)k0 * N + n0;
  dst += (size_t)e * dBS + (size_t)n0 * dLd + k0;
  int t = threadIdx.x;
  int c4 = t & 15, kr = t >> 4;            // 16 float4-cols x 16 rows per pass
#pragma unroll
  for (int i = 0; i < 4; ++i) {
    float4 v = *(const float4*)(src + (size_t)(kr + i * 16) * N + c4 * 4);
    tile[kr + i * 16][c4 * 4 + 0] = v.x;
    tile[kr + i * 16][c4 * 4 + 1] = v.y;
    tile[kr + i * 16][c4 * 4 + 2] = v.z;
    tile[kr + i * 16][c4 * 4 + 3] = v.w;
  }
  __syncthreads();
  int sub = t & 7, nl = t >> 3;            // 8 k-chunks x 32 n per pass
#pragma unroll
  for (int pass = 0; pass < 2; ++pass) {
    int n = nl + pass * 32;
    unsigned short v8[8];
#pragma unroll
    for (int j = 0; j < 8; ++j) v8[j] = f2bf(tile[sub * 8 + j][n]);
    *reinterpret_cast<s8v*>(dst + (size_t)n * dLd + sub * 8) =
        *reinterpret_cast<const s8v*>(v8);
  }
}

__global__ void softmax_k(const float* __restrict__ logits, const float* __restrict__ qb,
                          const int* __restrict__ task, float* __restrict__ attn,
                          float* __restrict__ lossOut) {
  int b = blockIdx.x * blockDim.x + threadIdx.x;
  int t = task[b];
  float l[NE];
  float mx = -1e30f;
#pragma unroll
  for (int e = 0; e < NE; ++e) { l[e] = logits[b * NE + e] + qb[e * NT + t]; mx = fmaxf(mx, l[e]); }
  float s = 0.f;
#pragma unroll
  for (int e = 0; e < NE; ++e) { l[e] = expf(l[e] - mx); s += l[e]; }
  float inv = 1.f / s;
  float loss = 0.f;
#pragma unroll
  for (int e = 0; e < NE; ++e) {
    float a = l[e] * inv;
    attn[b * NE + e] = a;
    float lg = logf(a + 1e-10f);
    loss += fminf(fmaxf(lg, -6.f), 0.f);
  }
  for (int off = 1; off < 64; off <<= 1) loss += __shfl_xor(loss, off, 64);
  if ((threadIdx.x & 63) == 0) atomicAdd(lossOut, loss * (-0.3f / NB));
}

// tower_in[b,k] = sum_e attn[b,e] * bv1[e,k]   (rank-16 bias init)
__global__ void towerbias_k(const float* __restrict__ attn, const float* __restrict__ bv1,
                            float* __restrict__ towerin) {
  int idx = blockIdx.x * blockDim.x + threadIdx.x;
  if (idx >= NB * DK) return;
  int b = idx >> 9, k = idx & (DK - 1);
  float s = 0.f;
#pragma unroll
  for (int e = 0; e < NE; ++e) s += attn[b * NE + e] * bv1[e * DK + k];
  towerin[idx] = s;
}

// ti = bf16(twin + P0 + P1 + P2 + P3), 8 elems/thread
__global__ void cvt_ti_k(const float* __restrict__ twin, const float* __restrict__ P,
                         unsigned short* __restrict__ ti) {
  int idx = (blockIdx.x * blockDim.x + threadIdx.x) * 8;
  if (idx >= NB * DK) return;
  float v[8];
#pragma unroll
  for (int j = 0; j < 8; ++j) v[j] = twin[idx + j];
#pragma unroll
  for (int c = 0; c < 4; ++c) {
    const float* p = P + (size_t)c * NB * DK + idx;
#pragma unroll
    for (int j = 0; j < 8; ++j) v[j] += p[j];
  }
  unsigned short v8[8];
#pragma unroll
  for (int j = 0; j < 8; ++j) v8[j] = f2bf(v[j]);
  *reinterpret_cast<s8v*>(ti + idx) = *reinterpret_cast<const s8v*>(v8);
}

// wave per row: q[b] = h2[b,:] . Wt2 + bt2
__global__ void qfinal_k(const unsigned short* __restrict__ h2, const float* __restrict__ Wt2,
                         const float* __restrict__ bt2, float* __restrict__ out) {
  int w = (blockIdx.x * blockDim.x + threadIdx.x) >> 6;
  int lane = threadIdx.x & 63;
  if (w >= NB) return;
  float s = 0.f;
#pragma unroll
  for (int j = 0; j < 4; ++j) {
    int k = lane * 4 + j;
    s += bf2f(h2[(size_t)w * 256 + k]) * Wt2[k];
  }
  for (int off = 1; off < 64; off <<= 1) s += __shfl_xor(s, off, 64);
  if (lane == 0) out[w] = s + bt2[0];
}

// ---------------------------------------------------------------------------
extern "C" void kernel_launch(void* const* d_in, const int* in_sizes, int n_in,
                              void* d_out, int out_size, void* d_ws, size_t ws_size,
                              hipStream_t stream) {
  const float* state  = (const float*)d_in[0];
  const float* act    = (const float*)d_in[1];
  const float* rep_W0 = (const float*)d_in[2];
  const float* rep_b0 = (const float*)d_in[3];
  const float* rep_W1 = (const float*)d_in[4];
  const float* rep_b1 = (const float*)d_in[5];
  const float* emb    = (const float*)d_in[6];
  const float* Wk0    = (const float*)d_in[7];
  const float* bk0    = (const float*)d_in[8];
  const float* Wk1    = (const float*)d_in[9];
  const float* bk1    = (const float*)d_in[10];
  const float* Wv0    = (const float*)d_in[11];
  const float* bv0    = (const float*)d_in[12];
  const float* Wv1    = (const float*)d_in[13];
  const float* bv1    = (const float*)d_in[14];
  const float* Wt0    = (const float*)d_in[15];
  const float* bt0    = (const float*)d_in[16];
  const float* Wt1    = (const float*)d_in[17];
  const float* bt1    = (const float*)d_in[18];
  const float* Wt2    = (const float*)d_in[19];
  const float* bt2    = (const float*)d_in[20];
  float* out = (float*)d_out;

  char* wsb = (char*)d_ws;
  size_t off = 0;
  auto alloc = [&](size_t bytes) -> void* {
    void* p = wsb + off;
    off += (bytes + 255) & ~(size_t)255;
    return p;
  };
  unsigned short* Ap    = (unsigned short*)alloc((size_t)NB * 8192 * 2);       // scaled hv, 8 experts
  unsigned short* Wk0t  = (unsigned short*)alloc((size_t)NE * DREP * DH * 2);
  unsigned short* Wv0t  = (unsigned short*)alloc((size_t)NE * DREP * DH * 2);
  unsigned short* Wv1t  = (unsigned short*)alloc((size_t)DK * (NE * DH) * 2);  // [n][e*1024+h]
  float*          P     = (float*)alloc((size_t)4 * NB * DK * 4);              // split-K partials
  unsigned short* h0    = (unsigned short*)alloc((size_t)NB * DREP * 2);
  unsigned short* rep   = (unsigned short*)alloc((size_t)NB * DREP * 2);
  float*          twin  = (float*)alloc((size_t)NB * DK * 4);
  unsigned short* xbuf  = (unsigned short*)alloc((size_t)NB * XK * 2);
  unsigned short* ti    = (unsigned short*)alloc((size_t)NB * DK * 2);
  unsigned short* h1    = (unsigned short*)alloc((size_t)NB * 512 * 2);
  unsigned short* h2    = (unsigned short*)alloc((size_t)NB * 256 * 2);
  unsigned short* rW1t  = (unsigned short*)alloc((size_t)DREP * DREP * 2);
  unsigned short* rW0t  = (unsigned short*)alloc((size_t)DREP * XK * 2);
  float*          qk1   = (float*)alloc((size_t)NE * NT * DH * 4);
  unsigned short* Wt0t  = (unsigned short*)alloc((size_t)512 * 512 * 2);
  unsigned short* Wt1t  = (unsigned short*)alloc((size_t)256 * 512 * 2);
  float*          logits= (float*)alloc((size_t)NB * NE * 4);
  float*          attn  = (float*)alloc((size_t)NB * NE * 4);
  float*          Qt    = (float*)alloc((size_t)NT * DK * 4);
  int*            task  = (int*)alloc((size_t)NB * 4);
  float*          qb    = (float*)alloc((size_t)NE * NT * 4);

  hipMemsetAsync(logits, 0, (size_t)NB * NE * 4, stream);
  hipMemsetAsync(out + NB, 0, sizeof(float), stream);

  task_k<<<NB / 256, 256, 0, stream>>>(state, task);
  buildx_k<<<(NB * XK + 255) / 256, 256, 0, stream>>>(state, act, xbuf);
  prep_emb_k<<<NT, 256, 0, stream>>>(emb, bk1, Qt, qb);
  qk1_k<<<NE * DH / 4, 256, 0, stream>>>(Wk1, Qt, qk1);

  // transposes: grid (N/64, K/64, E)
  convT_k<<<dim3(DREP / 64, XK / 64, 1), 256, 0, stream>>>(rep_W0, rW0t, DREP, 0, 0, XK);
  convT_k<<<dim3(DREP / 64, DREP / 64, 1), 256, 0, stream>>>(rep_W1, rW1t, DREP, 0, 0, DREP);
  convT_k<<<dim3(DH / 64, DREP / 64, NE), 256, 0, stream>>>(Wk0, Wk0t, DH, (long)DREP * DH, (long)DREP * DH, DREP);
  convT_k<<<dim3(DH / 64, DREP / 64, NE), 256, 0, stream>>>(Wv0, Wv0t, DH, (long)DREP * DH, (long)DREP * DH, DREP);
  convT_k<<<dim3(DK / 64, DH / 64, NE), 256, 0, stream>>>(Wv1, Wv1t, DK, (long)DH * DK, 1024L, NE * DH);
  convT_k<<<dim3(512 / 64, 512 / 64, 1), 256, 0, stream>>>(Wt0, Wt0t, 512, 0, 0, 512);
  convT_k<<<dim3(256 / 64, 512 / 64, 1), 256, 0, stream>>>(Wt1, Wt1t, 256, 0, 0, 512);

  // rep MLP
  gemm_k<128, 128, 0, 1, XK, XK, XK><<<dim3(NB / 128, DREP / 128, 1), 256, 0, stream>>>(
      xbuf, rW0t, rep_b0, h0, DREP, nullptr, nullptr, nullptr, 0, nullptr, nullptr);
  gemm_k<128, 128, 0, 0, DREP, DREP, DREP><<<dim3(NB / 128, DREP / 128, 1), 256, 0, stream>>>(
      h0, rW1t, rep_b1, rep, DREP, nullptr, nullptr, nullptr, 0, nullptr, nullptr);

  // K-pass: hk fused into logits
  gemm_k<128, 128, 1, 1, DREP, DREP, DREP><<<dim3(NB / 128, DH / 128, NE), 256, 0, stream>>>(
      rep, Wk0t, bk0, nullptr, 0, qk1, task, logits, 0, nullptr, nullptr);

  softmax_k<<<NB / 256, 256, 0, stream>>>(logits, qb, task, attn, out + NB);
  towerbias_k<<<NB * DK / 256, 256, 0, stream>>>(attn, bv1, twin);

  // V-pass + split-K accumulate into per-chunk partials (race-free, no atomics)
  for (int g = 0; g < 2; ++g) {
    gemm_k<128, 128, 2, 1, DREP, DREP, DREP><<<dim3(NB / 128, DH / 128, 8), 256, 0, stream>>>(
        rep, Wv0t, bv0, Ap, 8192, nullptr, nullptr, nullptr, g * 8, attn, nullptr);
    if (g == 0)
      gemm_k<128, 128, 3, 0, 8192, NE * DH, 2048><<<dim3(NB / 128, DK / 128, 4), 256, 0, stream>>>(
          Ap, Wv1t, nullptr, nullptr, 0, nullptr, nullptr, nullptr, 0, nullptr, P);
    else
      gemm_k<128, 128, 4, 0, 8192, NE * DH, 2048><<<dim3(NB / 128, DK / 128, 4), 256, 0, stream>>>(
          Ap, Wv1t + (size_t)8192, nullptr, nullptr, 0, nullptr, nullptr, nullptr, 0, nullptr, P);
  }
  cvt_ti_k<<<(NB * DK / 8 + 255) / 256, 256, 0, stream>>>(twin, P, ti);

  // tower
  gemm_k<64, 64, 0, 1, DK, DK, DK><<<dim3(NB / 64, 512 / 64, 1), 256, 0, stream>>>(
      ti, Wt0t, bt0, h1, 512, nullptr, nullptr, nullptr, 0, nullptr, nullptr);
  gemm_k<64, 64, 0, 1, 512, 512, 512><<<dim3(NB / 64, 256 / 64, 1), 256, 0, stream>>>(
      h1, Wt1t, bt1, h2, 256, nullptr, nullptr, nullptr, 0, nullptr, nullptr);
  qfinal_k<<<NB / 4, 256, 0, stream>>>(h2, Wt2, bt2, out);
}